// Round 5
// baseline (1967.772 us; speedup 1.0000x reference)
//
#include <hip/hip_runtime.h>
#include <hip/hip_fp8.h>

// Problem constants
#define NB   2048   // batch
#define SEQ  168    // encoder steps
#define NF   7      // features
#define NH   128    // hidden
#define G4   512    // 4*NH gate rows
#define NP   96     // decoder steps
#define ROWS 4      // batch rows per block (padded to M=16 for MFMA); grid=512 -> 2 blocks/CU
#define NTHR 512
#define KE   160    // enc A/B K: [x 0..6][pad 7][h 8..135][pad 136..159]
#define KD   256    // dec A/B K: [combine 0..127][prev_h 128..255]
#define KA   160    // att A/B K: [h 0..127][y 128..134][pad 135..159]
#define HXS  168    // h16 row stride for MFMA-A tiles (336B -> 2-way banks, free)
#define CTS  264    // sh_cath row stride in h16 (528B -> 2-way)
#define PRS  513    // sh_pre row stride in f32

typedef _Float16 h16;
typedef _Float16 h16x2 __attribute__((ext_vector_type(2)));
typedef _Float16 h16x4 __attribute__((ext_vector_type(4)));
typedef _Float16 h16x8 __attribute__((ext_vector_type(8)));
typedef float    f32x2 __attribute__((ext_vector_type(2)));
typedef float    f32x4 __attribute__((ext_vector_type(4)));
typedef unsigned int u32x4 __attribute__((ext_vector_type(4)));

// -------- d_ws layout (bytes). Total ~44.6 MB. --------
constexpr size_t WENC_OFF = 0;        // h16[512][160]
constexpr size_t WDEC_OFF = 163840;   // h16[512][256]
constexpr size_t WATT_OFF = 425984;   // h16[168][160]  [h|y|0-pad]
constexpr size_t BENC_OFF = 479744;   // f32[512]
constexpr size_t BDEC_OFF = 481792;   // f32[512]
constexpr size_t ENC_OFF  = 524288;   // fp8[NB*SEQ*NH] encoder outputs (44 MB), scaled x16

__device__ __forceinline__ float sigm(float x) { return 1.f / (1.f + __expf(-x)); }
__device__ __forceinline__ float tanh_(float x) {
  float e = __expf(-2.f * fabsf(x));
  return copysignf((1.f - e) / (1.f + e), x);
}

// force a preloaded fragment to stay register-resident (opaque def kills remat)
__device__ __forceinline__ void keepreg(h16x8& v) {
  u32x4& u = reinterpret_cast<u32x4&>(v);
  asm volatile("" : "+v"(u));
}
__device__ __forceinline__ void keepreg(float& v) { asm volatile("" : "+v"(v)); }

// fp8 e4m3 pack/unpack (HW cvt on gfx950)
__device__ __forceinline__ unsigned char pack_fp8(float x) {
#if __has_builtin(__builtin_amdgcn_cvt_pk_fp8_f32)
  int v = __builtin_amdgcn_cvt_pk_fp8_f32(x, 0.f, 0, false);
  return (unsigned char)(v & 0xff);
#else
  __hip_fp8_e4m3 q(x);
  return *(unsigned char*)&q;
#endif
}
template <bool HI>
__device__ __forceinline__ f32x2 unp2(unsigned int w) {
#if __has_builtin(__builtin_amdgcn_cvt_pk_f32_fp8)
  return __builtin_amdgcn_cvt_pk_f32_fp8(w, HI);   // HI constant
#else
  __hip_fp8_e4m3 a, b;
  constexpr unsigned int sh = HI ? 16 : 0;
  *(unsigned char*)&a = (w >> sh) & 0xff;
  *(unsigned char*)&b = (w >> (sh + 8)) & 0xff;
  f32x2 r; r.x = (float)a; r.y = (float)b; return r;
#endif
}

// -------- setup: cast/pack weights into ws --------
__global__ void setup_weights(const float* __restrict__ Wih_enc, const float* __restrict__ Whh_enc,
                              const float* __restrict__ Wih_dec, const float* __restrict__ Whh_dec,
                              const float* __restrict__ Watt,
                              const float* __restrict__ bihe, const float* __restrict__ bhhe,
                              const float* __restrict__ bihd, const float* __restrict__ bhhd,
                              char* __restrict__ ws) {
  int idx = blockIdx.x * blockDim.x + threadIdx.x;
  if (idx < 81920) {
    int n = idx / KE, k = idx % KE;
    float v = 0.f;
    if (k < NF) v = Wih_enc[n * NF + k];
    else if (k >= 8 && k < 136) v = Whh_enc[n * NH + (k - 8)];
    ((h16*)(ws + WENC_OFF))[idx] = (h16)v;
  } else if (idx < 81920 + 131072) {
    int i = idx - 81920;
    int n = i / KD, k = i % KD;
    float v = (k < NH) ? Wih_dec[n * NH + k] : Whh_dec[n * NH + (k - NH)];
    ((h16*)(ws + WDEC_OFF))[i] = (h16)v;
  } else if (idx < 81920 + 131072 + 26880) {
    int i = idx - (81920 + 131072);
    int k = i % KA, s = i / KA;
    float v = (k < NH + NF) ? Watt[s * (NH + NF) + k] : 0.f;
    ((h16*)(ws + WATT_OFF))[i] = (h16)v;
  } else if (idx < 81920 + 131072 + 26880 + 512) {
    int g = idx - (81920 + 131072 + 26880);
    ((float*)(ws + BENC_OFF))[g] = bihe[g] + bhhe[g];
    ((float*)(ws + BDEC_OFF))[g] = bihd[g] + bhhd[g];
  }
}

// -------- main persistent kernel: 4 batch rows/block, 512 blocks (2/CU) --------
__global__ __launch_bounds__(NTHR, 2)
void encdec_kernel(const float* __restrict__ xb, const float* __restrict__ b_att,
                   const float* __restrict__ Wout, const float* __restrict__ bout,
                   const float* __restrict__ Wfin, const float* __restrict__ bfin,
                   const h16* __restrict__ w16enc, const h16* __restrict__ w16dec,
                   const h16* __restrict__ watt, const float* __restrict__ bencp,
                   const float* __restrict__ bdecp, unsigned char* __restrict__ enc8,
                   float* __restrict__ out) {
  __shared__ alignas(16) h16   sh_hx[16][HXS];      // MFMA A (enc), rows 4-15 zero   5376 B
  __shared__ alignas(16) float sh_c[ROWS][NH];      //                                2048 B
  __shared__ alignas(16) float sh_pre[ROWS][PRS];   //                                8208 B
  __shared__ alignas(16) float sh_ph[ROWS][NH];     //                                2048 B
  __shared__ alignas(16) h16   sh_ainh[16][HXS];    // MFMA A (att)                   5376 B
  __shared__ alignas(16) h16   sh_cath[16][CTS];    // MFMA A (dec)                   8448 B
  __shared__ alignas(16) float sh_attw[ROWS][SEQ];  //                                2688 B
  __shared__ alignas(16) float sh_out[ROWS][8];     //                                 128 B
  __shared__ alignas(16) h16   sh_watt2[40][HXS];   // W_att rows 128..167           13440 B
  // total ~47.8 KB static -> 2 blocks/CU

  const int t  = threadIdx.x;
  const int r0 = blockIdx.x * ROWS;

  // init LDS
  for (int i = t; i < 16 * HXS; i += NTHR) {
    int r = i / HXS, k = i % HXS;
    float v = 0.f;
    if (r < ROWS && k < NF) v = xb[((size_t)(r0 + r) * SEQ + 0) * NF + k];
    sh_hx[r][k] = (h16)v;
    sh_ainh[r][k] = (h16)0.f;
  }
  for (int i = t; i < ROWS * NH; i += NTHR) { int r = i >> 7, k = i & 127; sh_c[r][k] = 0.f; }
  for (int i = t; i < 12 * CTS; i += NTHR) { int r = i / CTS, k = i % CTS; sh_cath[ROWS + r][k] = (h16)0.f; }
  for (int i = t; i < 40 * KA; i += NTHR)  { int r = i / KA, k = i % KA; sh_watt2[r][k] = watt[(128 + r) * KA + k]; }

  // wave/lane decomposition for MFMA
  const int w  = t >> 6;   // wave id: owns gate slice [w*64, w*64+64)
  const int l  = t & 63;
  const int lq = l >> 4;
  const int ln = l & 15;

  // preload enc B fragments -> regs (pinned)
  h16x8 bfE[4][5];
  float bE[4];
  #pragma unroll
  for (int nt = 0; nt < 4; ++nt) {
    int n = w * 64 + nt * 16 + ln;
    bE[nt] = bencp[n];
    keepreg(bE[nt]);
    #pragma unroll
    for (int kt = 0; kt < 5; ++kt) {
      bfE[nt][kt] = *(const h16x8*)(w16enc + n * KE + kt * 32 + lq * 8);
      keepreg(bfE[nt][kt]);
    }
  }

  const int hh = t & 127;  // elementwise: 1 (row, h) per thread
  const int er_ = t >> 7;  // elementwise row 0..3

  __syncthreads();

  // ================= encoder: 168 steps =================
  for (int s = 0; s < SEQ; ++s) {
    float xnext = (hh < NF && s + 1 < SEQ) ? xb[((size_t)(r0 + er_) * SEQ + s + 1) * NF + hh] : 0.f;

    // E1: pre = [x|h] @ W_enc^T via MFMA (M=16 padded, 4 real rows)
    {
      h16x8 af[5];
      #pragma unroll
      for (int kt = 0; kt < 5; ++kt)
        af[kt] = *(const h16x8*)(&sh_hx[ln][kt * 32 + lq * 8]);
      #pragma unroll
      for (int nt = 0; nt < 4; ++nt) {
        f32x4 acc = {0.f, 0.f, 0.f, 0.f};
        #pragma unroll
        for (int kt = 0; kt < 5; ++kt)
          acc = __builtin_amdgcn_mfma_f32_16x16x32_f16(af[kt], bfE[nt][kt], acc, 0, 0, 0);
        int n = w * 64 + nt * 16 + ln;
        if (lq == 0) {   // rows 0..3 live in quad 0
          #pragma unroll
          for (int reg = 0; reg < 4; ++reg)
            sh_pre[reg][n] = acc[reg] + bE[nt];
        }
      }
    }
    __syncthreads();

    // E2: LSTM cell elementwise (1 element/thread); fp8 history store
    {
      int r = er_;
      float gi = sigm(sh_pre[r][hh]);
      float gf = sigm(sh_pre[r][hh + 128]);
      float gg = tanh_(sh_pre[r][hh + 256]);
      float go = sigm(sh_pre[r][hh + 384]);
      float c = gf * sh_c[r][hh] + gi * gg;
      float h = go * tanh_(c);
      sh_c[r][hh] = c;
      sh_hx[r][8 + hh] = (h16)h;
      sh_ph[r][hh] = h;
      enc8[((size_t)(r0 + r) * SEQ + s) * NH + hh] = pack_fp8(h * 16.f);
      if (hh < NF && s + 1 < SEQ) sh_hx[r][hh] = (h16)xnext;
    }
    __syncthreads();
  }

  // preload dec + att B fragments (enc frags dead), pinned
  h16x8 bfD[4][8];
  float bD[4];
  #pragma unroll
  for (int nt = 0; nt < 4; ++nt) {
    int n = w * 64 + nt * 16 + ln;
    bD[nt] = bdecp[n];
    keepreg(bD[nt]);
    #pragma unroll
    for (int kt = 0; kt < 8; ++kt) {
      bfD[nt][kt] = *(const h16x8*)(w16dec + n * KD + kt * 32 + lq * 8);
      keepreg(bfD[nt][kt]);
    }
  }
  h16x8 bfA[5];          // W_att tile w
  {
    int sA = w * 16 + ln;   // < 128
    #pragma unroll
    for (int kt = 0; kt < 5; ++kt) {
      bfA[kt] = *(const h16x8*)(watt + sA * KA + kt * 32 + lq * 8);
      keepreg(bfA[kt]);
    }
  }
  float battR = b_att[w * 16 + ln];
  keepreg(battR);
  const int s2 = 128 + w * 16 + ln;
  float batt2 = (w < 3 && s2 < SEQ) ? b_att[s2] : 0.f;
  keepreg(batt2);

  // decoder init
  {
    int r = er_;
    h16 hv = sh_hx[r][8 + hh];
    sh_cath[r][128 + hh] = hv;
    sh_ainh[r][hh] = hv;
  }
  if (t < ROWS * NF) {
    int r = t / 7, f = t - (t / 7) * 7;
    sh_ainh[r][128 + f] = (h16)xb[((size_t)(r0 + r) * SEQ + (SEQ - 1)) * NF + f];  // y0
  }
  __syncthreads();

  // decoder per-thread constants
  const int sl = t & 31;          // D2 lane
  const int sr = t >> 5;          // D2 row (t<128)
  const int cr = w >> 1;          // D3 row (wave pair)
  const int hf = w & 1;           //     h-half
  const int o  = l & 15;          //     h-quad within half
  const int sg = l >> 4;          //     s-segment (42 each)
  const int orow = t / 7;         // D6
  const int ocol = t - (t / 7) * 7;

  // ================= decoder: 96 steps =================
  for (int p = 0; p < NP; ++p) {
    // D1: logits = attn_in @ W_att^T via MFMA (M=16, N=168, K=160)
    {
      h16x8 afA[5];
      #pragma unroll
      for (int kt = 0; kt < 5; ++kt)
        afA[kt] = *(const h16x8*)(&sh_ainh[ln][kt * 32 + lq * 8]);
      f32x4 acc = {0.f, 0.f, 0.f, 0.f};
      #pragma unroll
      for (int kt = 0; kt < 5; ++kt)
        acc = __builtin_amdgcn_mfma_f32_16x16x32_f16(afA[kt], bfA[kt], acc, 0, 0, 0);
      int s1 = w * 16 + ln;
      if (lq == 0) {
        #pragma unroll
        for (int reg = 0; reg < 4; ++reg)
          sh_attw[reg][s1] = acc[reg] + battR;
      }
      if (w < 3) {   // tiles 8-10 (s in [128,168)); B frags from LDS
        int srow = (s2 < SEQ ? s2 : SEQ - 1) - 128;
        f32x4 acc2 = {0.f, 0.f, 0.f, 0.f};
        #pragma unroll
        for (int kt = 0; kt < 5; ++kt) {
          h16x8 bf2 = *(const h16x8*)(&sh_watt2[srow][kt * 32 + lq * 8]);
          acc2 = __builtin_amdgcn_mfma_f32_16x16x32_f16(afA[kt], bf2, acc2, 0, 0, 0);
        }
        if (s2 < SEQ && lq == 0) {
          #pragma unroll
          for (int reg = 0; reg < 4; ++reg)
            sh_attw[reg][s2] = acc2[reg] + batt2;
        }
      }
    }
    __syncthreads();

    // D2: softmax over s (4 rows x 32 lanes)
    if (t < 32 * ROWS) {
      float vals[6];
      float m = -1e30f;
      #pragma unroll
      for (int j = 0; j < 6; ++j) {
        int s = sl + 32 * j;
        vals[j] = (s < SEQ) ? sh_attw[sr][s] : -1e30f;
        m = fmaxf(m, vals[j]);
      }
      #pragma unroll
      for (int off = 16; off > 0; off >>= 1) m = fmaxf(m, __shfl_xor(m, off, 32));
      float sum = 0.f;
      #pragma unroll
      for (int j = 0; j < 6; ++j) {
        float e = __expf(vals[j] - m);
        e = (sl + 32 * j < SEQ) ? e : 0.f;
        vals[j] = e;
        sum += e;
      }
      #pragma unroll
      for (int off = 16; off > 0; off >>= 1) sum += __shfl_xor(sum, off, 32);
      float inv = 1.f / sum;
      #pragma unroll
      for (int j = 0; j < 6; ++j) {
        int s = sl + 32 * j;
        if (s < SEQ) sh_attw[sr][s] = vals[j] * inv;
      }
    }
    __syncthreads();

    // D3: combine[r][h] = sum_s w[r][s]*enc8[r][s][h]
    // wave pair per row: wave = (row, h-half); lane = (s-segment, h-quad); in-wave shfl reduce
    {
      const unsigned char* er = enc8 + ((size_t)(r0 + cr) * SEQ) * NH + hf * 64 + o * 4;
      float a[4] = {0.f, 0.f, 0.f, 0.f};
      const int sbeg = sg * 42;
      #pragma unroll 3
      for (int si = 0; si < 42; ++si) {
        int s = sbeg + si;
        float wg = sh_attw[cr][s];
        unsigned int ev = *(const unsigned int*)(er + (size_t)s * NH);
        f32x2 p0 = unp2<false>(ev);
        f32x2 p1 = unp2<true>(ev);
        a[0] += wg * p0.x; a[1] += wg * p0.y;
        a[2] += wg * p1.x; a[3] += wg * p1.y;
      }
      #pragma unroll
      for (int j = 0; j < 4; ++j) { a[j] += __shfl_xor(a[j], 16); a[j] += __shfl_xor(a[j], 32); }
      if (sg == 0) {
        h16x4 cv;
        #pragma unroll
        for (int j = 0; j < 4; ++j) cv[j] = (h16)(a[j] * 0.0625f);  // /16 scale
        *(h16x4*)(&sh_cath[cr][hf * 64 + o * 4]) = cv;
      }
    }
    __syncthreads();

    // D4: gates = [combine|prev_h] @ W_dec^T via MFMA (K=256)
    {
      h16x8 af[8];
      #pragma unroll
      for (int kt = 0; kt < 8; ++kt)
        af[kt] = *(const h16x8*)(&sh_cath[ln][kt * 32 + lq * 8]);
      #pragma unroll
      for (int nt = 0; nt < 4; ++nt) {
        f32x4 acc = {0.f, 0.f, 0.f, 0.f};
        #pragma unroll
        for (int kt = 0; kt < 8; ++kt)
          acc = __builtin_amdgcn_mfma_f32_16x16x32_f16(af[kt], bfD[nt][kt], acc, 0, 0, 0);
        int n = w * 64 + nt * 16 + ln;
        if (lq == 0) {
          #pragma unroll
          for (int reg = 0; reg < 4; ++reg)
            sh_pre[reg][n] = acc[reg] + bD[nt];
        }
      }
    }
    __syncthreads();

    // D5: c_new = sigm(f)*prev_h + sigm(i)*tanh(g)
    {
      int r = er_;
      float gi = sigm(sh_pre[r][hh]);
      float gf = sigm(sh_pre[r][hh + 128]);
      float gg = tanh_(sh_pre[r][hh + 256]);
      float cn = gf * sh_ph[r][hh] + gi * gg;
      sh_ph[r][hh] = cn;
      h16 ch = (h16)cn;
      sh_cath[r][128 + hh] = ch;  // prev_h for next D4
      sh_ainh[r][hh] = ch;        // attn_in for next D1
    }
    __syncthreads();

    // D6: out[r][f] = c_new . W_out[f] + b_out[f]
    if (t < ROWS * NF) {
      float a = bout[ocol];
      const float* wr = Wout + ocol * NH;
      #pragma unroll 8
      for (int k = 0; k < NH; k += 4) {
        float4 pv = *(const float4*)&sh_ph[orow][k];
        float4 wv = *(const float4*)(wr + k);
        a += pv.x * wv.x + pv.y * wv.y + pv.z * wv.z + pv.w * wv.w;
      }
      sh_out[orow][ocol] = a;
      sh_ainh[orow][128 + ocol] = (h16)a;  // y_prev for next D1
    }
    __syncthreads();

    // D7: final[b][p] = out . W_fin + b_fin (no trailing barrier: next write to
    // sh_out is D6(p+1), >=5 barriers away)
    if (t < ROWS) {
      float a = bfin[0];
      #pragma unroll
      for (int f = 0; f < NF; ++f) a += sh_out[t][f] * Wfin[f];
      out[(size_t)(r0 + t) * NP + p] = a;
    }
  }
}

extern "C" void kernel_launch(void* const* d_in, const int* in_sizes, int n_in,
                              void* d_out, int out_size, void* d_ws, size_t ws_size,
                              hipStream_t stream) {
  const float* xb      = (const float*)d_in[0];
  const float* Wih_enc = (const float*)d_in[1];
  const float* Whh_enc = (const float*)d_in[2];
  const float* bih_enc = (const float*)d_in[3];
  const float* bhh_enc = (const float*)d_in[4];
  const float* Watt    = (const float*)d_in[5];
  const float* batt    = (const float*)d_in[6];
  const float* Wih_dec = (const float*)d_in[7];
  const float* Whh_dec = (const float*)d_in[8];
  const float* bih_dec = (const float*)d_in[9];
  const float* bhh_dec = (const float*)d_in[10];
  const float* Wout    = (const float*)d_in[11];
  const float* bout    = (const float*)d_in[12];
  const float* Wfin    = (const float*)d_in[13];
  const float* bfin    = (const float*)d_in[14];
  char* ws = (char*)d_ws;  // needs ~44.6 MB

  // 81920 + 131072 + 26880 + 512 = 240384 elements = 939 * 256
  setup_weights<<<939, 256, 0, stream>>>(Wih_enc, Whh_enc, Wih_dec, Whh_dec, Watt,
                                         bih_enc, bhh_enc, bih_dec, bhh_dec, ws);
  encdec_kernel<<<NB / ROWS, NTHR, 0, stream>>>(
      xb, batt, Wout, bout, Wfin, bfin,
      (const h16*)(ws + WENC_OFF), (const h16*)(ws + WDEC_OFF),
      (const h16*)(ws + WATT_OFF), (const float*)(ws + BENC_OFF),
      (const float*)(ws + BDEC_OFF), (unsigned char*)(ws + ENC_OFF),
      (float*)d_out);
}

// Round 6
// 1385.282 us; speedup vs baseline: 1.4205x; 1.4205x over previous
//
#include <hip/hip_runtime.h>
#include <hip/hip_fp8.h>

// Problem constants
#define NB   2048   // batch
#define SEQ  168    // encoder steps
#define NF   7      // features
#define NH   128    // hidden
#define NP   96     // decoder steps
#define ROWS 8      // batch rows per block (padded to M=16 for MFMA); grid=256
#define NTHR 512
#define KE   160    // enc A/B K: [x 0..6][pad 7][h 8..135][pad 136..159]
#define KD   256    // dec A/B K: [combine 0..127][prev_h 128..255]
#define KA   160    // att A/B K: [h 0..127][y 128..134][pad 135..159]
#define HXS  168    // h16 row stride for MFMA-A tiles (336B -> 2-way banks, free)
#define CTS  264    // sh_cath row stride in h16 (528B -> 2-way)

typedef _Float16 h16;
typedef _Float16 h16x8 __attribute__((ext_vector_type(8)));
typedef float    f32x2 __attribute__((ext_vector_type(2)));
typedef float    f32x4 __attribute__((ext_vector_type(4)));
typedef unsigned int u32x4 __attribute__((ext_vector_type(4)));

// -------- d_ws layout (bytes). Total ~44.6 MB. --------
constexpr size_t WENC_OFF = 0;        // h16[512][160]
constexpr size_t WDEC_OFF = 163840;   // h16[512][256]
constexpr size_t WATT_OFF = 425984;   // h16[168][160]  [h|y|0-pad]
constexpr size_t BENC_OFF = 479744;   // f32[512]
constexpr size_t BDEC_OFF = 481792;   // f32[512]
constexpr size_t ENC_OFF  = 524288;   // fp8[NB*SEQ*NH] encoder outputs (44 MB), scaled x16

__device__ __forceinline__ float sigm(float x) { return 1.f / (1.f + __expf(-x)); }
__device__ __forceinline__ float tanh_(float x) {
  float e = __expf(-2.f * fabsf(x));
  return copysignf((1.f - e) / (1.f + e), x);
}

__device__ __forceinline__ void keepreg(h16x8& v) {
  u32x4& u = reinterpret_cast<u32x4&>(v);
  asm volatile("" : "+v"(u));
}
__device__ __forceinline__ void keepreg(float& v) { asm volatile("" : "+v"(v)); }

// fp8 e4m3 pack/unpack (HW cvt on gfx950)
__device__ __forceinline__ unsigned char pack_fp8(float x) {
#if __has_builtin(__builtin_amdgcn_cvt_pk_fp8_f32)
  int v = __builtin_amdgcn_cvt_pk_fp8_f32(x, 0.f, 0, false);
  return (unsigned char)(v & 0xff);
#else
  __hip_fp8_e4m3 q(x);
  return *(unsigned char*)&q;
#endif
}
template <bool HI>
__device__ __forceinline__ f32x2 unp2(unsigned int w) {
#if __has_builtin(__builtin_amdgcn_cvt_pk_f32_fp8)
  return __builtin_amdgcn_cvt_pk_f32_fp8(w, HI);
#else
  __hip_fp8_e4m3 a, b;
  constexpr unsigned int sh = HI ? 16 : 0;
  *(unsigned char*)&a = (w >> sh) & 0xff;
  *(unsigned char*)&b = (w >> (sh + 8)) & 0xff;
  f32x2 r; r.x = (float)a; r.y = (float)b; return r;
#endif
}

// -------- setup: cast/pack weights into ws --------
__global__ void setup_weights(const float* __restrict__ Wih_enc, const float* __restrict__ Whh_enc,
                              const float* __restrict__ Wih_dec, const float* __restrict__ Whh_dec,
                              const float* __restrict__ Watt,
                              const float* __restrict__ bihe, const float* __restrict__ bhhe,
                              const float* __restrict__ bihd, const float* __restrict__ bhhd,
                              char* __restrict__ ws) {
  int idx = blockIdx.x * blockDim.x + threadIdx.x;
  if (idx < 81920) {
    int n = idx / KE, k = idx % KE;
    float v = 0.f;
    if (k < NF) v = Wih_enc[n * NF + k];
    else if (k >= 8 && k < 136) v = Whh_enc[n * NH + (k - 8)];
    ((h16*)(ws + WENC_OFF))[idx] = (h16)v;
  } else if (idx < 81920 + 131072) {
    int i = idx - 81920;
    int n = i / KD, k = i % KD;
    float v = (k < NH) ? Wih_dec[n * NH + k] : Whh_dec[n * NH + (k - NH)];
    ((h16*)(ws + WDEC_OFF))[i] = (h16)v;
  } else if (idx < 81920 + 131072 + 26880) {
    int i = idx - (81920 + 131072);
    int k = i % KA, s = i / KA;
    float v = (k < NH + NF) ? Watt[s * (NH + NF) + k] : 0.f;
    ((h16*)(ws + WATT_OFF))[i] = (h16)v;
  } else if (idx < 81920 + 131072 + 26880 + 512) {
    int g = idx - (81920 + 131072 + 26880);
    ((float*)(ws + BENC_OFF))[g] = bihe[g] + bhhe[g];
    ((float*)(ws + BDEC_OFF))[g] = bihd[g] + bhhd[g];
  }
}

// -------- main persistent kernel: 8 rows/block, fused MFMA+cell, reg-resident state --------
__global__ __launch_bounds__(NTHR, 2)
void encdec_kernel(const float* __restrict__ xb, const float* __restrict__ b_att,
                   const float* __restrict__ Wout, const float* __restrict__ bout,
                   const float* __restrict__ Wfin, const float* __restrict__ bfin,
                   const h16* __restrict__ w16enc, const h16* __restrict__ w16dec,
                   const h16* __restrict__ watt, const float* __restrict__ bencp,
                   const float* __restrict__ bdecp, unsigned char* __restrict__ enc8,
                   float* __restrict__ out) {
  __shared__ alignas(16) h16   sh_hx[2][16][HXS];   // MFMA A (enc), ping-pong      10752 B
  __shared__ alignas(16) float sh_ph[ROWS][NH];     // fp32 decoder cell for D6      4096 B
  __shared__ alignas(16) h16   sh_ainh[16][HXS];    // MFMA A (att): [h|y|0]         5376 B
  __shared__ alignas(16) h16   sh_cath[2][16][CTS]; // MFMA A (dec), ping-pong      16896 B
  __shared__ alignas(16) float sh_attw[ROWS][SEQ];  //                               5376 B
  __shared__ alignas(16) float sh_out[ROWS][8];     //                                256 B
  __shared__ alignas(16) h16   sh_watt2[40][HXS];   // W_att rows 128..167          13440 B
  // total ~56.2 KB static

  const int t  = threadIdx.x;
  const int r0 = blockIdx.x * ROWS;

  // init LDS (zero MFMA-A tiles incl. pad rows/cols; stage x(0))
  for (int i = t; i < 2 * 16 * HXS; i += NTHR) ((h16*)sh_hx)[i] = (h16)0.f;
  for (int i = t; i < 16 * HXS; i += NTHR)     ((h16*)sh_ainh)[i] = (h16)0.f;
  for (int i = t; i < 2 * 16 * CTS; i += NTHR) ((h16*)sh_cath)[i] = (h16)0.f;
  for (int i = t; i < 40 * KA; i += NTHR) { int r = i / KA, k = i % KA; sh_watt2[r][k] = watt[(128 + r) * KA + k]; }
  if (t < ROWS * NF) {
    int r = t / NF, f = t - (t / NF) * NF;
    sh_hx[0][r][f] = (h16)xb[((size_t)(r0 + r) * SEQ + 0) * NF + f];
  }

  // wave/lane decomposition: wave w owns h-column slice [w*16, w*16+16)
  const int w  = t >> 6;
  const int l  = t & 63;
  const int lq = l >> 4;          // quad -> C rows lq*4..lq*4+3
  const int ln = l & 15;          // C col within tile
  const int hcol = w * 16 + ln;   // hidden index this lane owns
  const int mrow = lq * 4;
  const bool act = (lq < 2);      // rows 0..7 real

  // preload enc B fragments: gate g tile at n = g*128 + hcol (fused-cell mapping)
  h16x8 bfE[4][5];
  float bE[4];
  #pragma unroll
  for (int g = 0; g < 4; ++g) {
    int n = g * 128 + hcol;
    bE[g] = bencp[n];
    keepreg(bE[g]);
    #pragma unroll
    for (int kt = 0; kt < 5; ++kt) {
      bfE[g][kt] = *(const h16x8*)(w16enc + n * KE + kt * 32 + lq * 8);
      keepreg(bfE[g][kt]);
    }
  }

  float creg[4] = {0.f, 0.f, 0.f, 0.f};   // LSTM cell state c, register-resident
  float hlast[4] = {0.f, 0.f, 0.f, 0.f};  // last h (for decoder init)

  __syncthreads();

  // ================= encoder: 168 steps, ONE barrier/step =================
  for (int s = 0; s < SEQ; ++s) {
    const int cur = s & 1;
    // x(s+1) prefetch (56 threads of wave 0; overlaps MFMA)
    float xn = 0.f;
    if (t < ROWS * NF && s + 1 < SEQ)
      xn = xb[((size_t)(r0 + t / NF) * SEQ + s + 1) * NF + (t - (t / NF) * NF)];

    // E1: pre = [x|h] @ W_enc^T via MFMA; gates land in this lane's registers
    h16x8 af[5];
    #pragma unroll
    for (int kt = 0; kt < 5; ++kt)
      af[kt] = *(const h16x8*)(&sh_hx[cur][ln][kt * 32 + lq * 8]);
    f32x4 ac[4];
    #pragma unroll
    for (int g = 0; g < 4; ++g) {
      f32x4 a = {0.f, 0.f, 0.f, 0.f};
      #pragma unroll
      for (int kt = 0; kt < 5; ++kt)
        a = __builtin_amdgcn_mfma_f32_16x16x32_f16(af[kt], bfE[g][kt], a, 0, 0, 0);
      ac[g] = a;
    }

    // E2 fused: cell update in-register; h -> ping-pong buffer + fp8 history
    if (act) {
      #pragma unroll
      for (int reg = 0; reg < 4; ++reg) {
        float gi = sigm(ac[0][reg] + bE[0]);
        float gf = sigm(ac[1][reg] + bE[1]);
        float gg = tanh_(ac[2][reg] + bE[2]);
        float go = sigm(ac[3][reg] + bE[3]);
        float c = gf * creg[reg] + gi * gg;
        creg[reg] = c;
        float h = go * tanh_(c);
        hlast[reg] = h;
        sh_hx[cur ^ 1][mrow + reg][8 + hcol] = (h16)h;
        enc8[((size_t)(r0 + mrow + reg) * SEQ + s) * NH + hcol] = pack_fp8(h * 16.f);
      }
    }
    if (t < ROWS * NF && s + 1 < SEQ)
      sh_hx[cur ^ 1][t / NF][t - (t / NF) * NF] = (h16)xn;
    __syncthreads();
  }

  // preload dec B fragments: only gates i,f,g (o unused) -> 96 regs, 24 MFMA/step
  h16x8 bfD[3][8];
  float bD[3];
  #pragma unroll
  for (int g = 0; g < 3; ++g) {
    int n = g * 128 + hcol;
    bD[g] = bdecp[n];
    keepreg(bD[g]);
    #pragma unroll
    for (int kt = 0; kt < 8; ++kt) {
      bfD[g][kt] = *(const h16x8*)(w16dec + n * KD + kt * 32 + lq * 8);
      keepreg(bfD[g][kt]);
    }
  }
  h16x8 bfA[5];          // W_att tile: row s1 = hcol
  #pragma unroll
  for (int kt = 0; kt < 5; ++kt) {
    bfA[kt] = *(const h16x8*)(watt + hcol * KA + kt * 32 + lq * 8);
    keepreg(bfA[kt]);
  }
  float battR = b_att[hcol];
  keepreg(battR);
  const int s2v = 128 + hcol;
  float batt2 = (w < 3 && s2v < SEQ) ? b_att[s2v] : 0.f;
  keepreg(batt2);

  // decoder init: h_T from registers; creg becomes the decoder cell carry
  if (act) {
    #pragma unroll
    for (int reg = 0; reg < 4; ++reg) {
      creg[reg] = hlast[reg];
      sh_cath[0][mrow + reg][128 + hcol] = (h16)hlast[reg];
      sh_ainh[mrow + reg][hcol] = (h16)hlast[reg];
    }
  }
  if (t < ROWS * NF) {
    int r = t / NF, f = t - (t / NF) * NF;
    sh_ainh[r][128 + f] = (h16)xb[((size_t)(r0 + r) * SEQ + (SEQ - 1)) * NF + f];  // y0
  }
  __syncthreads();

  // decoder per-thread constants
  const int sl = t & 31;          // D2
  const int sr = t >> 5;
  const int cr = t >> 6;          // D3: wave = row
  const int o  = t & 15;          //     h-octet
  const int q4 = (t >> 4) & 3;    //     s-quadrant
  const int orow = t / 7;         // D6
  const int ocol = t - (t / 7) * 7;

  // ================= decoder: 96 steps, 5 barriers/step =================
  for (int p = 0; p < NP; ++p) {
    const int CA = p & 1;
    // D1: logits = attn_in @ W_att^T via MFMA (M=16, N=168, K=160)
    {
      h16x8 afA[5];
      #pragma unroll
      for (int kt = 0; kt < 5; ++kt)
        afA[kt] = *(const h16x8*)(&sh_ainh[ln][kt * 32 + lq * 8]);
      f32x4 acc = {0.f, 0.f, 0.f, 0.f};
      #pragma unroll
      for (int kt = 0; kt < 5; ++kt)
        acc = __builtin_amdgcn_mfma_f32_16x16x32_f16(afA[kt], bfA[kt], acc, 0, 0, 0);
      if (act) {
        #pragma unroll
        for (int reg = 0; reg < 4; ++reg)
          sh_attw[mrow + reg][hcol] = acc[reg] + battR;
      }
      if (w < 3) {   // s in [128,168): B frags from LDS copy
        int srow = (s2v < SEQ ? s2v : SEQ - 1) - 128;
        f32x4 acc2 = {0.f, 0.f, 0.f, 0.f};
        #pragma unroll
        for (int kt = 0; kt < 5; ++kt) {
          h16x8 bf2 = *(const h16x8*)(&sh_watt2[srow][kt * 32 + lq * 8]);
          acc2 = __builtin_amdgcn_mfma_f32_16x16x32_f16(afA[kt], bf2, acc2, 0, 0, 0);
        }
        if (s2v < SEQ && act) {
          #pragma unroll
          for (int reg = 0; reg < 4; ++reg)
            sh_attw[mrow + reg][s2v] = acc2[reg] + batt2;
        }
      }
    }
    __syncthreads();

    // D2: softmax over s (8 rows x 32 lanes)
    if (t < 256) {
      float vals[6];
      float m = -1e30f;
      #pragma unroll
      for (int j = 0; j < 6; ++j) {
        int s = sl + 32 * j;
        vals[j] = (s < SEQ) ? sh_attw[sr][s] : -1e30f;
        m = fmaxf(m, vals[j]);
      }
      #pragma unroll
      for (int off = 16; off > 0; off >>= 1) m = fmaxf(m, __shfl_xor(m, off, 32));
      float sum = 0.f;
      #pragma unroll
      for (int j = 0; j < 6; ++j) {
        float e = __expf(vals[j] - m);
        e = (sl + 32 * j < SEQ) ? e : 0.f;
        vals[j] = e;
        sum += e;
      }
      #pragma unroll
      for (int off = 16; off > 0; off >>= 1) sum += __shfl_xor(sum, off, 32);
      float inv = 1.f / sum;
      #pragma unroll
      for (int j = 0; j < 6; ++j) {
        int s = sl + 32 * j;
        if (s < SEQ) sh_attw[sr][s] = vals[j] * inv;
      }
    }
    __syncthreads();

    // D3: combine[r][h] = sum_s w[r][s]*enc8[r][s][h] -> cath[CA] combine region
    {
      const unsigned char* er = enc8 + ((size_t)(r0 + cr) * SEQ) * NH + o * 8;
      float a[8] = {0.f, 0.f, 0.f, 0.f, 0.f, 0.f, 0.f, 0.f};
      const int sbeg = q4 * 42;
      #pragma unroll 3
      for (int si = 0; si < 42; ++si) {
        int s = sbeg + si;
        float wg = sh_attw[cr][s];
        uint2 ev = *(const uint2*)(er + (size_t)s * NH);
        f32x2 p0 = unp2<false>(ev.x);
        f32x2 p1 = unp2<true>(ev.x);
        f32x2 p2 = unp2<false>(ev.y);
        f32x2 p3 = unp2<true>(ev.y);
        a[0] += wg * p0.x; a[1] += wg * p0.y;
        a[2] += wg * p1.x; a[3] += wg * p1.y;
        a[4] += wg * p2.x; a[5] += wg * p2.y;
        a[6] += wg * p3.x; a[7] += wg * p3.y;
      }
      #pragma unroll
      for (int j = 0; j < 8; ++j) { a[j] += __shfl_xor(a[j], 16); a[j] += __shfl_xor(a[j], 32); }
      if (q4 == 0) {
        h16x8 cv;
        #pragma unroll
        for (int j = 0; j < 8; ++j) cv[j] = (h16)(a[j] * 0.0625f);  // /16 scale
        *(h16x8*)(&sh_cath[CA][cr][o * 8]) = cv;
      }
    }
    __syncthreads();

    // D4+D5 fused: gates via MFMA (i,f,g only), cell update in-register,
    // prev_h -> cath[CA^1] (ping-pong), attn_in + fp32 cell -> LDS
    {
      h16x8 af[8];
      #pragma unroll
      for (int kt = 0; kt < 8; ++kt)
        af[kt] = *(const h16x8*)(&sh_cath[CA][ln][kt * 32 + lq * 8]);
      f32x4 ag[3];
      #pragma unroll
      for (int g = 0; g < 3; ++g) {
        f32x4 a = {0.f, 0.f, 0.f, 0.f};
        #pragma unroll
        for (int kt = 0; kt < 8; ++kt)
          a = __builtin_amdgcn_mfma_f32_16x16x32_f16(af[kt], bfD[g][kt], a, 0, 0, 0);
        ag[g] = a;
      }
      if (act) {
        #pragma unroll
        for (int reg = 0; reg < 4; ++reg) {
          float gi = sigm(ag[0][reg] + bD[0]);
          float gf = sigm(ag[1][reg] + bD[1]);
          float gg = tanh_(ag[2][reg] + bD[2]);
          float cn = gf * creg[reg] + gi * gg;
          creg[reg] = cn;
          sh_cath[CA ^ 1][mrow + reg][128 + hcol] = (h16)cn;
          sh_ainh[mrow + reg][hcol] = (h16)cn;
          sh_ph[mrow + reg][hcol] = cn;
        }
      }
    }
    __syncthreads();

    // D6: out[r][f] = c_new . W_out[f] + b_out[f]
    if (t < ROWS * NF) {
      float a = bout[ocol];
      const float* wr = Wout + ocol * NH;
      #pragma unroll 8
      for (int k = 0; k < NH; k += 4) {
        float4 pv = *(const float4*)&sh_ph[orow][k];
        float4 wv = *(const float4*)(wr + k);
        a += pv.x * wv.x + pv.y * wv.y + pv.z * wv.z + pv.w * wv.w;
      }
      sh_out[orow][ocol] = a;
      sh_ainh[orow][128 + ocol] = (h16)a;  // y_prev for next D1
    }
    __syncthreads();

    // D7: final[b][p] = out . W_fin + b_fin (no trailing barrier needed)
    if (t < ROWS) {
      float a = bfin[0];
      #pragma unroll
      for (int f = 0; f < NF; ++f) a += sh_out[t][f] * Wfin[f];
      out[(size_t)(r0 + t) * NP + p] = a;
    }
  }
}

extern "C" void kernel_launch(void* const* d_in, const int* in_sizes, int n_in,
                              void* d_out, int out_size, void* d_ws, size_t ws_size,
                              hipStream_t stream) {
  const float* xb      = (const float*)d_in[0];
  const float* Wih_enc = (const float*)d_in[1];
  const float* Whh_enc = (const float*)d_in[2];
  const float* bih_enc = (const float*)d_in[3];
  const float* bhh_enc = (const float*)d_in[4];
  const float* Watt    = (const float*)d_in[5];
  const float* batt    = (const float*)d_in[6];
  const float* Wih_dec = (const float*)d_in[7];
  const float* Whh_dec = (const float*)d_in[8];
  const float* bih_dec = (const float*)d_in[9];
  const float* bhh_dec = (const float*)d_in[10];
  const float* Wout    = (const float*)d_in[11];
  const float* bout    = (const float*)d_in[12];
  const float* Wfin    = (const float*)d_in[13];
  const float* bfin    = (const float*)d_in[14];
  char* ws = (char*)d_ws;  // needs ~44.6 MB

  // 81920 + 131072 + 26880 + 512 = 240384 elements = 939 * 256
  setup_weights<<<939, 256, 0, stream>>>(Wih_enc, Whh_enc, Wih_dec, Whh_dec, Watt,
                                         bih_enc, bhh_enc, bih_dec, bhh_dec, ws);
  encdec_kernel<<<NB / ROWS, NTHR, 0, stream>>>(
      xb, batt, Wout, bout, Wfin, bfin,
      (const h16*)(ws + WENC_OFF), (const h16*)(ws + WDEC_OFF),
      (const h16*)(ws + WATT_OFF), (const float*)(ws + BENC_OFF),
      (const float*)(ws + BDEC_OFF), (unsigned char*)(ws + ENC_OFF),
      (float*)d_out);
}

// Round 7
// 1314.904 us; speedup vs baseline: 1.4965x; 1.0535x over previous
//
#include <hip/hip_runtime.h>
#include <hip/hip_fp8.h>

// Problem constants
#define NB   2048   // batch
#define SEQ  168    // encoder steps
#define NF   7      // features
#define NH   128    // hidden
#define NP   96     // decoder steps
#define EROWS 8     // encoder rows/block -> 256 blocks
#define DROWS 4     // decoder rows/block -> 512 blocks (2 serial passes, hist fits LDS)
#define NTHR 512
#define KE   160    // enc A/B K: [x 0..6][pad 7][h 8..135][pad 136..159]
#define KD   256    // dec A/B K: [combine 0..127][prev_h 128..255]
#define KA   160    // att A/B K: [h 0..127][y 128..134][pad 135..159]
#define HXS  168    // h16 row stride for MFMA-A tiles
#define CTS  264    // cath row stride in h16
#define SP   144    // hist LDS row stride BYTES (16-aligned; 36 words -> 2-way banks)

typedef _Float16 h16;
typedef _Float16 h16x4 __attribute__((ext_vector_type(4)));
typedef _Float16 h16x8 __attribute__((ext_vector_type(8)));
typedef float    f32x2 __attribute__((ext_vector_type(2)));
typedef float    f32x4 __attribute__((ext_vector_type(4)));
typedef unsigned int u32x4 __attribute__((ext_vector_type(4)));

// -------- d_ws layout (bytes). Total ~45.6 MB. --------
constexpr size_t WENC_OFF = 0;         // h16[512][160]
constexpr size_t WDEC_OFF = 163840;    // h16[512][256]
constexpr size_t WATT_OFF = 425984;    // h16[168][160]
constexpr size_t BENC_OFF = 479744;    // f32[512]
constexpr size_t BDEC_OFF = 481792;    // f32[512]
constexpr size_t ENC_OFF  = 524288;    // fp8[NB*SEQ*NH] (44 MB), scaled x16
constexpr size_t HT_OFF   = 44564480;  // f32[NB*NH] final encoder h (1 MB)

// -------- decoder dynamic-LDS layout (bytes) --------
constexpr int HIST_OFF = 0;                       // fp8 hist[4][168][SP]   96768
constexpr int AINH_OFF = 96768;                   // h16[16][HXS]            5376
constexpr int CATH_OFF = 102144;                  // h16[2][16][CTS]        16896
constexpr int ATTW_OFF = 119040;                  // f32[4][SEQ]             2688
constexpr int WAT2_OFF = 121728;                  // h16[40][KA]            12800
constexpr int PH_OFF   = 134528;                  // f32[4][NH]              2048
constexpr int OUTB_OFF = 136576;                  // f32[4][8]                128
constexpr int DSMEM    = 136704;

__device__ __forceinline__ float sigm(float x) { return 1.f / (1.f + __expf(-x)); }
__device__ __forceinline__ float tanh_(float x) {
  float e = __expf(-2.f * fabsf(x));
  return copysignf((1.f - e) / (1.f + e), x);
}

// loop-carried opaque redefinition: call INSIDE the step loop to pin to VGPRs
__device__ __forceinline__ void keepreg(h16x8& v) {
  u32x4& u = reinterpret_cast<u32x4&>(v);
  asm volatile("" : "+v"(u));
}
__device__ __forceinline__ void keepreg(float& v) { asm volatile("" : "+v"(v)); }

__device__ __forceinline__ unsigned char pack_fp8(float x) {
#if __has_builtin(__builtin_amdgcn_cvt_pk_fp8_f32)
  int v = __builtin_amdgcn_cvt_pk_fp8_f32(x, 0.f, 0, false);
  return (unsigned char)(v & 0xff);
#else
  __hip_fp8_e4m3 q(x);
  return *(unsigned char*)&q;
#endif
}
template <bool HI>
__device__ __forceinline__ f32x2 unp2(unsigned int w) {
#if __has_builtin(__builtin_amdgcn_cvt_pk_f32_fp8)
  return __builtin_amdgcn_cvt_pk_f32_fp8(w, HI);
#else
  __hip_fp8_e4m3 a, b;
  constexpr unsigned int sh = HI ? 16 : 0;
  *(unsigned char*)&a = (w >> sh) & 0xff;
  *(unsigned char*)&b = (w >> (sh + 8)) & 0xff;
  f32x2 r; r.x = (float)a; r.y = (float)b; return r;
#endif
}

// -------- setup: cast/pack weights into ws --------
__global__ void setup_weights(const float* __restrict__ Wih_enc, const float* __restrict__ Whh_enc,
                              const float* __restrict__ Wih_dec, const float* __restrict__ Whh_dec,
                              const float* __restrict__ Watt,
                              const float* __restrict__ bihe, const float* __restrict__ bhhe,
                              const float* __restrict__ bihd, const float* __restrict__ bhhd,
                              char* __restrict__ ws) {
  int idx = blockIdx.x * blockDim.x + threadIdx.x;
  if (idx < 81920) {
    int n = idx / KE, k = idx % KE;
    float v = 0.f;
    if (k < NF) v = Wih_enc[n * NF + k];
    else if (k >= 8 && k < 136) v = Whh_enc[n * NH + (k - 8)];
    ((h16*)(ws + WENC_OFF))[idx] = (h16)v;
  } else if (idx < 81920 + 131072) {
    int i = idx - 81920;
    int n = i / KD, k = i % KD;
    float v = (k < NH) ? Wih_dec[n * NH + k] : Whh_dec[n * NH + (k - NH)];
    ((h16*)(ws + WDEC_OFF))[i] = (h16)v;
  } else if (idx < 81920 + 131072 + 26880) {
    int i = idx - (81920 + 131072);
    int k = i % KA, s = i / KA;
    float v = (k < NH + NF) ? Watt[s * (NH + NF) + k] : 0.f;
    ((h16*)(ws + WATT_OFF))[i] = (h16)v;
  } else if (idx < 81920 + 131072 + 26880 + 512) {
    int g = idx - (81920 + 131072 + 26880);
    ((float*)(ws + BENC_OFF))[g] = bihe[g] + bhhe[g];
    ((float*)(ws + BDEC_OFF))[g] = bihd[g] + bhhd[g];
  }
}

// ================= encoder kernel: 8 rows/block, 256 blocks, 1 barrier/step =================
__global__ __launch_bounds__(NTHR, 2)
void enc_kernel(const float* __restrict__ xb, const h16* __restrict__ w16enc,
                const float* __restrict__ bencp, unsigned char* __restrict__ enc8,
                float* __restrict__ hT) {
  __shared__ alignas(16) h16 sh_hx[2][16][HXS];   // ping-pong A tile  10752 B

  const int t  = threadIdx.x;
  const int r0 = blockIdx.x * EROWS;

  for (int i = t; i < 2 * 16 * HXS; i += NTHR) ((h16*)sh_hx)[i] = (h16)0.f;
  __syncthreads();
  if (t < EROWS * NF) {
    int r = t / NF, f = t - (t / NF) * NF;
    sh_hx[0][r][f] = (h16)xb[((size_t)(r0 + r) * SEQ + 0) * NF + f];
  }

  const int w  = t >> 6;
  const int l  = t & 63;
  const int lq = l >> 4;
  const int ln = l & 15;
  const int hcol = w * 16 + ln;
  const int mrow = lq * 4;
  const bool act = (lq < 2);   // rows 0..7 real

  // preload enc B fragments (pinned in-loop below)
  h16x8 bfE[4][5];
  float bE[4];
  #pragma unroll
  for (int g = 0; g < 4; ++g) {
    int n = g * 128 + hcol;
    bE[g] = bencp[n];
    #pragma unroll
    for (int kt = 0; kt < 5; ++kt)
      bfE[g][kt] = *(const h16x8*)(w16enc + n * KE + kt * 32 + lq * 8);
  }

  float creg[4] = {0.f, 0.f, 0.f, 0.f};
  float hlast[4] = {0.f, 0.f, 0.f, 0.f};

  // running store pointers (1 add/step instead of full addr math)
  size_t sp[4];
  #pragma unroll
  for (int reg = 0; reg < 4; ++reg)
    sp[reg] = ((size_t)(r0 + mrow + reg) * SEQ) * NH + hcol;

  __syncthreads();

  for (int s = 0; s < SEQ; ++s) {
    const int cur = s & 1;
    // pin weights: opaque redefinition each iteration -> VGPR-resident
    #pragma unroll
    for (int g = 0; g < 4; ++g) {
      keepreg(bE[g]);
      #pragma unroll
      for (int kt = 0; kt < 5; ++kt) keepreg(bfE[g][kt]);
    }

    float xn = 0.f;
    if (t < EROWS * NF && s + 1 < SEQ)
      xn = xb[((size_t)(r0 + t / NF) * SEQ + s + 1) * NF + (t - (t / NF) * NF)];

    h16x8 af[5];
    #pragma unroll
    for (int kt = 0; kt < 5; ++kt)
      af[kt] = *(const h16x8*)(&sh_hx[cur][ln][kt * 32 + lq * 8]);
    f32x4 ac[4];
    #pragma unroll
    for (int g = 0; g < 4; ++g) {
      f32x4 a = {0.f, 0.f, 0.f, 0.f};
      #pragma unroll
      for (int kt = 0; kt < 5; ++kt)
        a = __builtin_amdgcn_mfma_f32_16x16x32_f16(af[kt], bfE[g][kt], a, 0, 0, 0);
      ac[g] = a;
    }

    if (act) {
      #pragma unroll
      for (int reg = 0; reg < 4; ++reg) {
        float gi = sigm(ac[0][reg] + bE[0]);
        float gf = sigm(ac[1][reg] + bE[1]);
        float gg = tanh_(ac[2][reg] + bE[2]);
        float go = sigm(ac[3][reg] + bE[3]);
        float c = gf * creg[reg] + gi * gg;
        creg[reg] = c;
        float h = go * tanh_(c);
        hlast[reg] = h;
        sh_hx[cur ^ 1][mrow + reg][8 + hcol] = (h16)h;
        enc8[sp[reg]] = pack_fp8(h * 16.f);
        sp[reg] += NH;
      }
    }
    if (t < EROWS * NF && s + 1 < SEQ)
      sh_hx[cur ^ 1][t / NF][t - (t / NF) * NF] = (h16)xn;
    __syncthreads();
  }

  if (act) {
    #pragma unroll
    for (int reg = 0; reg < 4; ++reg)
      hT[(size_t)(r0 + mrow + reg) * NH + hcol] = hlast[reg];
  }
}

// ================= decoder kernel: 4 rows/block, 512 blocks, hist in LDS =================
__global__ __launch_bounds__(NTHR, 1)
void dec_kernel(const float* __restrict__ xb, const float* __restrict__ b_att,
                const float* __restrict__ Wout, const float* __restrict__ bout,
                const float* __restrict__ Wfin, const float* __restrict__ bfin,
                const h16* __restrict__ w16dec, const h16* __restrict__ watt,
                const float* __restrict__ bdecp, const unsigned char* __restrict__ enc8,
                const float* __restrict__ hT, float* __restrict__ out) {
  extern __shared__ char smem[];
  char* hist = smem + HIST_OFF;                       // fp8 [4][168][SP bytes]
  h16*  sh_ainh = (h16*)(smem + AINH_OFF);            // [16][HXS]
  h16*  sh_cath = (h16*)(smem + CATH_OFF);            // [2][16][CTS]
  float* sh_attw = (float*)(smem + ATTW_OFF);         // [4][SEQ]
  h16*  sh_watt2 = (h16*)(smem + WAT2_OFF);           // [40][KA]
  float* sh_ph = (float*)(smem + PH_OFF);             // [4][NH]
  float* sh_out = (float*)(smem + OUTB_OFF);          // [4][8]

  const int t  = threadIdx.x;
  const int r0 = blockIdx.x * DROWS;

  // ---- init LDS ----
  for (int i = t; i < 16 * HXS; i += NTHR)      sh_ainh[i] = (h16)0.f;
  for (int i = t; i < 2 * 16 * CTS; i += NTHR)  sh_cath[i] = (h16)0.f;
  for (int i = t; i < 40 * KA; i += NTHR)       sh_watt2[i] = watt[128 * KA + i];
  // hist: one coalesced read of the block's 4x168x128 fp8 slice
  {
    const unsigned char* src = enc8 + (size_t)r0 * SEQ * NH;
    for (int i = t; i < (DROWS * SEQ * NH) / 16; i += NTHR) {
      int idx = i * 16;
      int r = idx / (SEQ * NH);
      int rem = idx - r * (SEQ * NH);
      int s = rem >> 7, ho = rem & 127;
      *(u32x4*)(hist + r * (SEQ * SP) + s * SP + ho) = *(const u32x4*)(src + idx);
    }
  }

  const int w  = t >> 6;
  const int l  = t & 63;
  const int lq = l >> 4;
  const int ln = l & 15;
  const int hcol = w * 16 + ln;
  const bool act = (lq == 0);   // rows 0..3 real

  // preload dec B fragments (i,f,g gates) + att fragments (pinned in-loop)
  h16x8 bfD[3][8];
  float bD[3];
  #pragma unroll
  for (int g = 0; g < 3; ++g) {
    int n = g * 128 + hcol;
    bD[g] = bdecp[n];
    #pragma unroll
    for (int kt = 0; kt < 8; ++kt)
      bfD[g][kt] = *(const h16x8*)(w16dec + n * KD + kt * 32 + lq * 8);
  }
  h16x8 bfA[5];
  #pragma unroll
  for (int kt = 0; kt < 5; ++kt)
    bfA[kt] = *(const h16x8*)(watt + hcol * KA + kt * 32 + lq * 8);
  float battR = b_att[hcol];
  const int s2v = 128 + hcol;
  float batt2 = (w < 3 && s2v < SEQ) ? b_att[s2v] : 0.f;

  // cell init from h_T; attn_in h-part; y0
  float creg[4] = {0.f, 0.f, 0.f, 0.f};
  if (act) {
    #pragma unroll
    for (int reg = 0; reg < 4; ++reg) {
      float hv = hT[(size_t)(r0 + reg) * NH + hcol];
      creg[reg] = hv;
      sh_cath[0 * 16 * CTS + reg * CTS + 128 + hcol] = (h16)hv;
      sh_ainh[reg * HXS + hcol] = (h16)hv;
    }
  }
  if (t < DROWS * NF) {
    int r = t / NF, f = t - (t / NF) * NF;
    sh_ainh[r * HXS + 128 + f] = (h16)xb[((size_t)(r0 + r) * SEQ + (SEQ - 1)) * NF + f];
  }
  __syncthreads();

  // per-thread constants
  const int sl = t & 31;          // D2
  const int sr = t >> 5;
  const int cr = w >> 1;          // D3: row
  const int hf = w & 1;           //     h-half (64 h)
  const int o  = l & 15;          //     uint within half
  const int sg = l >> 4;          //     s-segment (4 x 42)
  const char* hlane = hist + cr * (SEQ * SP) + hf * 64 + o * 4;
  const int orow = t / 7;         // D6
  const int ocol = t - (t / 7) * 7;

  for (int p = 0; p < NP; ++p) {
    const int CA = p & 1;
    // pin weights
    #pragma unroll
    for (int g = 0; g < 3; ++g) {
      keepreg(bD[g]);
      #pragma unroll
      for (int kt = 0; kt < 8; ++kt) keepreg(bfD[g][kt]);
    }
    #pragma unroll
    for (int kt = 0; kt < 5; ++kt) keepreg(bfA[kt]);
    keepreg(battR); keepreg(batt2);

    // D1: logits via MFMA (M=16, rows 0-3 real; N=168 split reg/LDS tiles)
    {
      h16x8 afA[5];
      #pragma unroll
      for (int kt = 0; kt < 5; ++kt)
        afA[kt] = *(const h16x8*)(sh_ainh + ln * HXS + kt * 32 + lq * 8);
      f32x4 acc = {0.f, 0.f, 0.f, 0.f};
      #pragma unroll
      for (int kt = 0; kt < 5; ++kt)
        acc = __builtin_amdgcn_mfma_f32_16x16x32_f16(afA[kt], bfA[kt], acc, 0, 0, 0);
      if (act) {
        #pragma unroll
        for (int reg = 0; reg < 4; ++reg)
          sh_attw[reg * SEQ + hcol] = acc[reg] + battR;
      }
      if (w < 3) {
        int srow = (s2v < SEQ ? s2v : SEQ - 1) - 128;
        f32x4 acc2 = {0.f, 0.f, 0.f, 0.f};
        #pragma unroll
        for (int kt = 0; kt < 5; ++kt) {
          h16x8 bf2 = *(const h16x8*)(sh_watt2 + srow * KA + kt * 32 + lq * 8);
          acc2 = __builtin_amdgcn_mfma_f32_16x16x32_f16(afA[kt], bf2, acc2, 0, 0, 0);
        }
        if (s2v < SEQ && act) {
          #pragma unroll
          for (int reg = 0; reg < 4; ++reg)
            sh_attw[reg * SEQ + s2v] = acc2[reg] + batt2;
        }
      }
    }
    __syncthreads();

    // D2: softmax over s (4 rows x 32 lanes)
    if (t < 32 * DROWS) {
      float vals[6];
      float m = -1e30f;
      #pragma unroll
      for (int j = 0; j < 6; ++j) {
        int s = sl + 32 * j;
        vals[j] = (s < SEQ) ? sh_attw[sr * SEQ + s] : -1e30f;
        m = fmaxf(m, vals[j]);
      }
      #pragma unroll
      for (int off = 16; off > 0; off >>= 1) m = fmaxf(m, __shfl_xor(m, off, 32));
      float sum = 0.f;
      #pragma unroll
      for (int j = 0; j < 6; ++j) {
        float e = __expf(vals[j] - m);
        e = (sl + 32 * j < SEQ) ? e : 0.f;
        vals[j] = e;
        sum += e;
      }
      #pragma unroll
      for (int off = 16; off > 0; off >>= 1) sum += __shfl_xor(sum, off, 32);
      float inv = 1.f / sum;
      #pragma unroll
      for (int j = 0; j < 6; ++j) {
        int s = sl + 32 * j;
        if (s < SEQ) sh_attw[sr * SEQ + s] = vals[j] * inv;
      }
    }
    __syncthreads();

    // D3: combine from LDS-resident hist (zero HBM traffic)
    {
      float a[4] = {0.f, 0.f, 0.f, 0.f};
      const char* hp = hlane + sg * 42 * SP;
      const float* wp = sh_attw + cr * SEQ + sg * 42;
      #pragma unroll 3
      for (int si = 0; si < 42; ++si) {
        float wg = wp[si];
        unsigned int ev = *(const unsigned int*)hp;
        hp += SP;
        f32x2 p0 = unp2<false>(ev);
        f32x2 p1 = unp2<true>(ev);
        a[0] += wg * p0.x; a[1] += wg * p0.y;
        a[2] += wg * p1.x; a[3] += wg * p1.y;
      }
      #pragma unroll
      for (int j = 0; j < 4; ++j) { a[j] += __shfl_xor(a[j], 16); a[j] += __shfl_xor(a[j], 32); }
      if (sg == 0) {
        h16x4 cv;
        #pragma unroll
        for (int j = 0; j < 4; ++j) cv[j] = (h16)(a[j] * 0.0625f);
        *(h16x4*)(sh_cath + CA * 16 * CTS + cr * CTS + hf * 64 + o * 4) = cv;
      }
    }
    __syncthreads();

    // D4+D5 fused: gates via MFMA (i,f,g), reg-resident cell, ping-pong prev_h
    {
      h16x8 af[8];
      #pragma unroll
      for (int kt = 0; kt < 8; ++kt)
        af[kt] = *(const h16x8*)(sh_cath + CA * 16 * CTS + ln * CTS + kt * 32 + lq * 8);
      f32x4 ag[3];
      #pragma unroll
      for (int g = 0; g < 3; ++g) {
        f32x4 a = {0.f, 0.f, 0.f, 0.f};
        #pragma unroll
        for (int kt = 0; kt < 8; ++kt)
          a = __builtin_amdgcn_mfma_f32_16x16x32_f16(af[kt], bfD[g][kt], a, 0, 0, 0);
        ag[g] = a;
      }
      if (act) {
        #pragma unroll
        for (int reg = 0; reg < 4; ++reg) {
          float gi = sigm(ag[0][reg] + bD[0]);
          float gf = sigm(ag[1][reg] + bD[1]);
          float gg = tanh_(ag[2][reg] + bD[2]);
          float cn = gf * creg[reg] + gi * gg;
          creg[reg] = cn;
          sh_cath[(CA ^ 1) * 16 * CTS + reg * CTS + 128 + hcol] = (h16)cn;
          sh_ainh[reg * HXS + hcol] = (h16)cn;
          sh_ph[reg * NH + hcol] = cn;
        }
      }
    }
    __syncthreads();

    // D6: out = c_new . W_out^T + b_out  (28 threads, wave 0)
    if (t < DROWS * NF) {
      float a = bout[ocol];
      const float* wr = Wout + ocol * NH;
      #pragma unroll 8
      for (int k = 0; k < NH; k += 4) {
        float4 pv = *(const float4*)(sh_ph + orow * NH + k);
        float4 wv = *(const float4*)(wr + k);
        a += pv.x * wv.x + pv.y * wv.y + pv.z * wv.z + pv.w * wv.w;
      }
      sh_out[orow * 8 + ocol] = a;
      sh_ainh[orow * HXS + 128 + ocol] = (h16)a;   // y_prev for next D1
    }
    // D7: same wave reads sh_out (in-order within wave 0) -> no extra barrier
    if (t < DROWS) {
      float a = bfin[0];
      #pragma unroll
      for (int f = 0; f < NF; ++f) a += sh_out[t * 8 + f] * Wfin[f];
      out[(size_t)(r0 + t) * NP + p] = a;
    }
    __syncthreads();   // ainh (D4+D6 writes) -> next D1
  }
}

extern "C" void kernel_launch(void* const* d_in, const int* in_sizes, int n_in,
                              void* d_out, int out_size, void* d_ws, size_t ws_size,
                              hipStream_t stream) {
  const float* xb      = (const float*)d_in[0];
  const float* Wih_enc = (const float*)d_in[1];
  const float* Whh_enc = (const float*)d_in[2];
  const float* bih_enc = (const float*)d_in[3];
  const float* bhh_enc = (const float*)d_in[4];
  const float* Watt    = (const float*)d_in[5];
  const float* batt    = (const float*)d_in[6];
  const float* Wih_dec = (const float*)d_in[7];
  const float* Whh_dec = (const float*)d_in[8];
  const float* bih_dec = (const float*)d_in[9];
  const float* bhh_dec = (const float*)d_in[10];
  const float* Wout    = (const float*)d_in[11];
  const float* bout    = (const float*)d_in[12];
  const float* Wfin    = (const float*)d_in[13];
  const float* bfin    = (const float*)d_in[14];
  char* ws = (char*)d_ws;  // needs ~45.6 MB

  static bool attr_set = false;
  (void)attr_set;  // set every call (idempotent, graph-capture safe host call)
  hipFuncSetAttribute(reinterpret_cast<const void*>(dec_kernel),
                      hipFuncAttributeMaxDynamicSharedMemorySize, DSMEM);

  setup_weights<<<939, 256, 0, stream>>>(Wih_enc, Whh_enc, Wih_dec, Whh_dec, Watt,
                                         bih_enc, bhh_enc, bih_dec, bhh_dec, ws);
  enc_kernel<<<NB / EROWS, NTHR, 0, stream>>>(
      xb, (const h16*)(ws + WENC_OFF), (const float*)(ws + BENC_OFF),
      (unsigned char*)(ws + ENC_OFF), (float*)(ws + HT_OFF));
  dec_kernel<<<NB / DROWS, NTHR, DSMEM, stream>>>(
      xb, batt, Wout, bout, Wfin, bfin,
      (const h16*)(ws + WDEC_OFF), (const h16*)(ws + WATT_OFF),
      (const float*)(ws + BDEC_OFF), (const unsigned char*)(ws + ENC_OFF),
      (const float*)(ws + HT_OFF), (float*)d_out);
}

// Round 8
// 1246.566 us; speedup vs baseline: 1.5786x; 1.0548x over previous
//
#include <hip/hip_runtime.h>
#include <hip/hip_fp8.h>

// Problem constants
#define NB   2048   // batch
#define SEQ  168    // encoder steps
#define NF   7      // features
#define NH   128    // hidden
#define NP   96     // decoder steps
#define EROWS 8     // encoder rows/block -> 256 blocks
#define DROWS 4     // decoder rows/block -> 512 blocks (2 passes; hist LDS-resident)
#define NTHR 512
#define KE   160    // enc A/B K: [x 0..6][pad 7][h 8..135][pad 136..159]
#define KD   256    // dec A/B K: [combine 0..127][prev_h 128..255]
#define KA   160    // att A/B K: [h 0..127][y 128..134][pad 135..159]
#define HXS  168    // h16 row stride for MFMA-A tiles
#define CTS  264    // cath row stride in h16

typedef _Float16 h16;
typedef _Float16 h16x8 __attribute__((ext_vector_type(8)));
typedef float    f32x2 __attribute__((ext_vector_type(2)));
typedef float    f32x4 __attribute__((ext_vector_type(4)));
typedef unsigned int u32x4 __attribute__((ext_vector_type(4)));

// -------- d_ws layout (bytes). Total ~45.6 MB. --------
constexpr size_t WENC_OFF = 0;         // h16[512][160]
constexpr size_t WDEC_OFF = 163840;    // h16[512][256]
constexpr size_t WATT_OFF = 425984;    // h16[168][160]
constexpr size_t BENC_OFF = 479744;    // f32[512]
constexpr size_t BDEC_OFF = 481792;    // f32[512]
constexpr size_t ENC_OFF  = 524288;    // u32[NB][42][128]: fp8x4 (s-packed) hist, x16 scale
constexpr size_t HT_OFF   = 44564480;  // f32[NB*NH] final encoder h (1 MB)

// -------- decoder dynamic-LDS layout (bytes) --------
constexpr int HIST_OFF = 0;        // u32[4][42][128]   86016
constexpr int AINH_OFF = 86016;    // h16[16][HXS]       5376
constexpr int CATH_OFF = 91392;    // h16[2][16][CTS]   16896
constexpr int ATTW_OFF = 108288;   // f32[4][168] e-vals 2688
constexpr int WAT2_OFF = 110976;   // h16[40][KA]       12800
constexpr int PH_OFF   = 123776;   // f32[4][NH]         2048
constexpr int OUTB_OFF = 125824;   // f32[4][8]           128
constexpr int DSMEM    = 125952;

__device__ __forceinline__ float sigm(float x) { return 1.f / (1.f + __expf(-x)); }
__device__ __forceinline__ float tanh_(float x) {
  float e = __expf(-2.f * fabsf(x));
  return copysignf((1.f - e) / (1.f + e), x);
}

// pack fp8(a),fp8(b) into the lo/hi half of a u32
template <bool HI>
__device__ __forceinline__ unsigned int pack2_fp8(float a, float b, unsigned int old) {
#if __has_builtin(__builtin_amdgcn_cvt_pk_fp8_f32)
  return (unsigned int)__builtin_amdgcn_cvt_pk_fp8_f32(a, b, (int)old, HI);
#else
  __hip_fp8_e4m3 qa(a), qb(b);
  unsigned int pair = (unsigned int)(*(unsigned char*)&qa) |
                      ((unsigned int)(*(unsigned char*)&qb) << 8);
  return HI ? ((old & 0x0000ffffu) | (pair << 16)) : ((old & 0xffff0000u) | pair);
#endif
}
template <bool HI>
__device__ __forceinline__ f32x2 unp2(unsigned int w) {
#if __has_builtin(__builtin_amdgcn_cvt_pk_f32_fp8)
  return __builtin_amdgcn_cvt_pk_f32_fp8(w, HI);
#else
  __hip_fp8_e4m3 a, b;
  constexpr unsigned int sh = HI ? 16 : 0;
  *(unsigned char*)&a = (w >> sh) & 0xff;
  *(unsigned char*)&b = (w >> (sh + 8)) & 0xff;
  f32x2 r; r.x = (float)a; r.y = (float)b; return r;
#endif
}

// -------- setup: cast/pack weights into ws --------
__global__ void setup_weights(const float* __restrict__ Wih_enc, const float* __restrict__ Whh_enc,
                              const float* __restrict__ Wih_dec, const float* __restrict__ Whh_dec,
                              const float* __restrict__ Watt,
                              const float* __restrict__ bihe, const float* __restrict__ bhhe,
                              const float* __restrict__ bihd, const float* __restrict__ bhhd,
                              char* __restrict__ ws) {
  int idx = blockIdx.x * blockDim.x + threadIdx.x;
  if (idx < 81920) {
    int n = idx / KE, k = idx % KE;
    float v = 0.f;
    if (k < NF) v = Wih_enc[n * NF + k];
    else if (k >= 8 && k < 136) v = Whh_enc[n * NH + (k - 8)];
    ((h16*)(ws + WENC_OFF))[idx] = (h16)v;
  } else if (idx < 81920 + 131072) {
    int i = idx - 81920;
    int n = i / KD, k = i % KD;
    float v = (k < NH) ? Wih_dec[n * NH + k] : Whh_dec[n * NH + (k - NH)];
    ((h16*)(ws + WDEC_OFF))[i] = (h16)v;
  } else if (idx < 81920 + 131072 + 26880) {
    int i = idx - (81920 + 131072);
    int k = i % KA, s = i / KA;
    float v = (k < NH + NF) ? Watt[s * (NH + NF) + k] : 0.f;
    ((h16*)(ws + WATT_OFF))[i] = (h16)v;
  } else if (idx < 81920 + 131072 + 26880 + 512) {
    int g = idx - (81920 + 131072 + 26880);
    ((float*)(ws + BENC_OFF))[g] = bihe[g] + bhhe[g];
    ((float*)(ws + BDEC_OFF))[g] = bihd[g] + bhhd[g];
  }
}

// ================= encoder: 8 rows/block, 256 blocks, 1 barrier/step =================
__global__ __launch_bounds__(NTHR, 1)
void enc_kernel(const float* __restrict__ xb, const h16* __restrict__ w16enc,
                const float* __restrict__ bencp, unsigned int* __restrict__ encw,
                float* __restrict__ hT) {
  __shared__ alignas(16) h16 sh_hx[2][16][HXS];   // ping-pong A tile  10752 B

  const int t  = threadIdx.x;
  const int r0 = blockIdx.x * EROWS;

  for (int i = t; i < 2 * 16 * HXS; i += NTHR) ((h16*)sh_hx)[i] = (h16)0.f;
  __syncthreads();
  if (t < EROWS * NF) {
    int r = t / NF, f = t - (t / NF) * NF;
    sh_hx[0][r][f] = (h16)xb[((size_t)(r0 + r) * SEQ + 0) * NF + f];
  }

  const int w  = t >> 6;
  const int l  = t & 63;
  const int lq = l >> 4;
  const int ln = l & 15;
  const int hcol = w * 16 + ln;
  const int mrow = lq * 4;
  const bool act = (lq < 2);   // rows 0..7 real

  // x-prefetch mapping: t<224: j = step-in-group, (xr,xf)
  const int j  = t & 3;
  const int rf = t >> 2;
  const int xr = rf / NF;
  const int xf = rf - xr * NF;

  // preload enc B fragments (AGPR/VGPR resident; no pinning games)
  h16x8 bfE[4][5];
  float bE[4];
  #pragma unroll
  for (int g = 0; g < 4; ++g) {
    int n = g * 128 + hcol;
    bE[g] = bencp[n];
    #pragma unroll
    for (int kt = 0; kt < 5; ++kt)
      bfE[g][kt] = *(const h16x8*)(w16enc + n * KE + kt * 32 + lq * 8);
  }

  float creg[4] = {0.f, 0.f, 0.f, 0.f};
  float hlast[4] = {0.f, 0.f, 0.f, 0.f};
  float hprev[4] = {0.f, 0.f, 0.f, 0.f};
  unsigned int hpack[4] = {0u, 0u, 0u, 0u};
  float xstash = 0.f;

  __syncthreads();

  for (int s = 0; s < SEQ; ++s) {
    const int cur = s & 1;
    // batched x prefetch: at s%4==0 load x for steps s+1..s+4
    if ((s & 3) == 0 && t < EROWS * NF * 4) {
      int sx = s + 1 + j;
      xstash = (sx < SEQ) ? xb[((size_t)(r0 + xr) * SEQ + sx) * NF + xf] : 0.f;
    }

    // E1: [x|h] @ W_enc^T via MFMA
    h16x8 af[5];
    #pragma unroll
    for (int kt = 0; kt < 5; ++kt)
      af[kt] = *(const h16x8*)(&sh_hx[cur][ln][kt * 32 + lq * 8]);
    f32x4 ac[4];
    #pragma unroll
    for (int g = 0; g < 4; ++g) {
      f32x4 a = {0.f, 0.f, 0.f, 0.f};
      #pragma unroll
      for (int kt = 0; kt < 5; ++kt)
        a = __builtin_amdgcn_mfma_f32_16x16x32_f16(af[kt], bfE[g][kt], a, 0, 0, 0);
      ac[g] = a;
    }

    // E2 fused cell; h to ping-pong; fp8 hist packed 4 steps -> 1 dword store
    if (act) {
      #pragma unroll
      for (int reg = 0; reg < 4; ++reg) {
        float gi = sigm(ac[0][reg] + bE[0]);
        float gf = sigm(ac[1][reg] + bE[1]);
        float gg = tanh_(ac[2][reg] + bE[2]);
        float go = sigm(ac[3][reg] + bE[3]);
        float c = gf * creg[reg] + gi * gg;
        creg[reg] = c;
        float h = go * tanh_(c);
        hlast[reg] = h;
        sh_hx[cur ^ 1][mrow + reg][8 + hcol] = (h16)h;
        float hs = h * 16.f;
        if ((s & 1) == 0) hprev[reg] = hs;
        else if ((s & 3) == 1) hpack[reg] = pack2_fp8<false>(hprev[reg], hs, hpack[reg]);
        else                   hpack[reg] = pack2_fp8<true>(hprev[reg], hs, hpack[reg]);
      }
      if ((s & 3) == 3) {
        int s4 = s >> 2;
        #pragma unroll
        for (int reg = 0; reg < 4; ++reg)
          encw[((size_t)(r0 + mrow + reg) * 42 + s4) * NH + hcol] = hpack[reg];
      }
    }
    if (t < EROWS * NF * 4 && (s & 3) == j && s + 1 < SEQ)
      sh_hx[cur ^ 1][xr][xf] = (h16)xstash;
    __syncthreads();
  }

  if (act) {
    #pragma unroll
    for (int reg = 0; reg < 4; ++reg)
      hT[(size_t)(r0 + mrow + reg) * NH + hcol] = hlast[reg];
  }
}

// ================= decoder: 4 rows/block, 512 blocks, hist in LDS, 4 barriers/step ======
__global__ __launch_bounds__(NTHR, 1)
void dec_kernel(const float* __restrict__ xb, const float* __restrict__ b_att,
                const float* __restrict__ Wout, const float* __restrict__ bout,
                const float* __restrict__ Wfin, const float* __restrict__ bfin,
                const h16* __restrict__ w16dec, const h16* __restrict__ watt,
                const float* __restrict__ bdecp, const unsigned int* __restrict__ encw,
                const float* __restrict__ hT, float* __restrict__ out) {
  extern __shared__ char smem[];
  unsigned int* hist = (unsigned int*)(smem + HIST_OFF);   // [4][42][128] u32
  h16*   sh_ainh  = (h16*)(smem + AINH_OFF);               // [16][HXS]
  h16*   sh_cath  = (h16*)(smem + CATH_OFF);               // [2][16][CTS]
  float* sh_attw  = (float*)(smem + ATTW_OFF);             // [4][168] e-values
  h16*   sh_watt2 = (h16*)(smem + WAT2_OFF);               // [40][KA]
  float* sh_ph    = (float*)(smem + PH_OFF);               // [4][NH]
  float* sh_out   = (float*)(smem + OUTB_OFF);             // [4][8]

  const int t  = threadIdx.x;
  const int r0 = blockIdx.x * DROWS;

  // ---- init LDS ----
  for (int i = t; i < 16 * HXS; i += NTHR)      sh_ainh[i] = (h16)0.f;
  for (int i = t; i < 2 * 16 * CTS; i += NTHR)  sh_cath[i] = (h16)0.f;
  for (int i = t; i < 40 * KA; i += NTHR)       sh_watt2[i] = watt[128 * KA + i];
  {
    const u32x4* src = (const u32x4*)(encw + (size_t)r0 * 42 * NH);
    for (int i = t; i < (DROWS * 42 * NH) / 4; i += NTHR)
      ((u32x4*)hist)[i] = src[i];
  }

  const int w  = t >> 6;
  const int l  = t & 63;
  const int lq = l >> 4;
  const int ln = l & 15;
  const int hcol = w * 16 + ln;
  const bool act = (lq == 0);   // rows 0..3 real

  // preload dec B fragments (i,f,g) + att fragments
  h16x8 bfD[3][8];
  float bD[3];
  #pragma unroll
  for (int g = 0; g < 3; ++g) {
    int n = g * 128 + hcol;
    bD[g] = bdecp[n];
    #pragma unroll
    for (int kt = 0; kt < 8; ++kt)
      bfD[g][kt] = *(const h16x8*)(w16dec + n * KD + kt * 32 + lq * 8);
  }
  h16x8 bfA[5];
  #pragma unroll
  for (int kt = 0; kt < 5; ++kt)
    bfA[kt] = *(const h16x8*)(watt + hcol * KA + kt * 32 + lq * 8);
  const float battR = b_att[hcol];
  const int s2v = 128 + hcol;
  const float batt2 = (w < 3 && s2v < SEQ) ? b_att[s2v] : 0.f;

  // cell init from h_T; attn_in h-part; y0
  float creg[4] = {0.f, 0.f, 0.f, 0.f};
  if (act) {
    #pragma unroll
    for (int reg = 0; reg < 4; ++reg) {
      float hv = hT[(size_t)(r0 + reg) * NH + hcol];
      creg[reg] = hv;
      sh_cath[0 * 16 * CTS + reg * CTS + 128 + hcol] = (h16)hv;
      sh_ainh[reg * HXS + hcol] = (h16)hv;
    }
  }
  if (t < DROWS * NF) {
    int r = t / NF, f = t - (t / NF) * NF;
    sh_ainh[r * HXS + 128 + f] = (h16)xb[((size_t)(r0 + r) * SEQ + (SEQ - 1)) * NF + f];
  }
  __syncthreads();

  // per-thread constants
  const int dr = t >> 7;          // D3: row (thread owns one (r,h))
  const int dh = t & 127;         //     h
  const unsigned int* hrow = hist + dr * (42 * NH) + dh;
  const float* erow = sh_attw + dr * SEQ;
  const int orow = t / 7;         // D6
  const int ocol = t - (t / 7) * 7;

  for (int p = 0; p < NP; ++p) {
    const int CA = p & 1;

    // D1: logits via MFMA; act lanes write e = exp(clamped logit) (no-max softmax)
    {
      h16x8 afA[5];
      #pragma unroll
      for (int kt = 0; kt < 5; ++kt)
        afA[kt] = *(const h16x8*)(sh_ainh + ln * HXS + kt * 32 + lq * 8);
      f32x4 acc = {0.f, 0.f, 0.f, 0.f};
      #pragma unroll
      for (int kt = 0; kt < 5; ++kt)
        acc = __builtin_amdgcn_mfma_f32_16x16x32_f16(afA[kt], bfA[kt], acc, 0, 0, 0);
      if (act) {
        #pragma unroll
        for (int reg = 0; reg < 4; ++reg) {
          float lg = fminf(fmaxf(acc[reg] + battR, -30.f), 30.f);
          sh_attw[reg * SEQ + hcol] = __expf(lg);
        }
      }
      if (w < 3) {
        int srow = (s2v < SEQ ? s2v : SEQ - 1) - 128;
        f32x4 acc2 = {0.f, 0.f, 0.f, 0.f};
        #pragma unroll
        for (int kt = 0; kt < 5; ++kt) {
          h16x8 bf2 = *(const h16x8*)(sh_watt2 + srow * KA + kt * 32 + lq * 8);
          acc2 = __builtin_amdgcn_mfma_f32_16x16x32_f16(afA[kt], bf2, acc2, 0, 0, 0);
        }
        if (s2v < SEQ && act) {
          #pragma unroll
          for (int reg = 0; reg < 4; ++reg) {
            float lg = fminf(fmaxf(acc2[reg] + batt2, -30.f), 30.f);
            sh_attw[reg * SEQ + s2v] = __expf(lg);
          }
        }
      }
    }
    __syncthreads();

    // D3 (+softmax norm): combine[r][h] = (Σ_s e_s v_s) / Σ_s e_s; thread owns (r,h)
    {
      f32x2 av = {0.f, 0.f};
      f32x2 es = {0.f, 0.f};
      #pragma unroll 6
      for (int s4 = 0; s4 < 42; ++s4) {
        unsigned int ev = hrow[s4 * NH];
        float4 e4 = *(const float4*)(erow + s4 * 4);   // broadcast
        f32x2 p01 = unp2<false>(ev);
        f32x2 p23 = unp2<true>(ev);
        f32x2 w01 = {e4.x, e4.y};
        f32x2 w23 = {e4.z, e4.w};
        av = w01 * p01 + av;
        av = w23 * p23 + av;
        es = es + w01;
        es = es + w23;
      }
      float inv = 0.0625f / (es.x + es.y);   // /16 fp8 scale folded in
      sh_cath[CA * 16 * CTS + dr * CTS + dh] = (h16)((av.x + av.y) * inv);
    }
    __syncthreads();

    // D4+D5 fused: gates via MFMA (i,f,g), reg-resident cell, ping-pong prev_h
    {
      h16x8 af[8];
      #pragma unroll
      for (int kt = 0; kt < 8; ++kt)
        af[kt] = *(const h16x8*)(sh_cath + CA * 16 * CTS + ln * CTS + kt * 32 + lq * 8);
      f32x4 ag[3];
      #pragma unroll
      for (int g = 0; g < 3; ++g) {
        f32x4 a = {0.f, 0.f, 0.f, 0.f};
        #pragma unroll
        for (int kt = 0; kt < 8; ++kt)
          a = __builtin_amdgcn_mfma_f32_16x16x32_f16(af[kt], bfD[g][kt], a, 0, 0, 0);
        ag[g] = a;
      }
      if (act) {
        #pragma unroll
        for (int reg = 0; reg < 4; ++reg) {
          float gi = sigm(ag[0][reg] + bD[0]);
          float gf = sigm(ag[1][reg] + bD[1]);
          float gg = tanh_(ag[2][reg] + bD[2]);
          float cn = gf * creg[reg] + gi * gg;
          creg[reg] = cn;
          sh_cath[(CA ^ 1) * 16 * CTS + reg * CTS + 128 + hcol] = (h16)cn;
          sh_ainh[reg * HXS + hcol] = (h16)cn;
          sh_ph[reg * NH + hcol] = cn;
        }
      }
    }
    __syncthreads();

    // D6: out = c_new . W_out^T + b_out (wave 0); D7 in-wave after
    if (t < DROWS * NF) {
      float a = bout[ocol];
      const float* wr = Wout + ocol * NH;
      #pragma unroll 8
      for (int k = 0; k < NH; k += 4) {
        float4 pv = *(const float4*)(sh_ph + orow * NH + k);
        float4 wv = *(const float4*)(wr + k);
        a += pv.x * wv.x + pv.y * wv.y + pv.z * wv.z + pv.w * wv.w;
      }
      sh_out[orow * 8 + ocol] = a;
      sh_ainh[orow * HXS + 128 + ocol] = (h16)a;   // y_prev for next D1
    }
    if (t < DROWS) {
      float a = bfin[0];
      #pragma unroll
      for (int f = 0; f < NF; ++f) a += sh_out[t * 8 + f] * Wfin[f];
      out[(size_t)(r0 + t) * NP + p] = a;
    }
    __syncthreads();   // ainh/cath writes -> next D1/D4
  }
}

extern "C" void kernel_launch(void* const* d_in, const int* in_sizes, int n_in,
                              void* d_out, int out_size, void* d_ws, size_t ws_size,
                              hipStream_t stream) {
  const float* xb      = (const float*)d_in[0];
  const float* Wih_enc = (const float*)d_in[1];
  const float* Whh_enc = (const float*)d_in[2];
  const float* bih_enc = (const float*)d_in[3];
  const float* bhh_enc = (const float*)d_in[4];
  const float* Watt    = (const float*)d_in[5];
  const float* batt    = (const float*)d_in[6];
  const float* Wih_dec = (const float*)d_in[7];
  const float* Whh_dec = (const float*)d_in[8];
  const float* bih_dec = (const float*)d_in[9];
  const float* bhh_dec = (const float*)d_in[10];
  const float* Wout    = (const float*)d_in[11];
  const float* bout    = (const float*)d_in[12];
  const float* Wfin    = (const float*)d_in[13];
  const float* bfin    = (const float*)d_in[14];
  char* ws = (char*)d_ws;  // needs ~45.6 MB

  hipFuncSetAttribute(reinterpret_cast<const void*>(dec_kernel),
                      hipFuncAttributeMaxDynamicSharedMemorySize, DSMEM);

  setup_weights<<<939, 256, 0, stream>>>(Wih_enc, Whh_enc, Wih_dec, Whh_dec, Watt,
                                         bih_enc, bhh_enc, bih_dec, bhh_dec, ws);
  enc_kernel<<<NB / EROWS, NTHR, 0, stream>>>(
      xb, (const h16*)(ws + WENC_OFF), (const float*)(ws + BENC_OFF),
      (unsigned int*)(ws + ENC_OFF), (float*)(ws + HT_OFF));
  dec_kernel<<<NB / DROWS, NTHR, DSMEM, stream>>>(
      xb, batt, Wout, bout, Wfin, bfin,
      (const h16*)(ws + WDEC_OFF), (const h16*)(ws + WATT_OFF),
      (const float*)(ws + BDEC_OFF), (const unsigned int*)(ws + ENC_OFF),
      (const float*)(ws + HT_OFF), (float*)d_out);
}

// Round 9
// 1208.427 us; speedup vs baseline: 1.6284x; 1.0316x over previous
//
#include <hip/hip_runtime.h>
#include <hip/hip_fp8.h>

// Problem constants
#define NB   2048   // batch
#define SEQ  168    // encoder steps
#define NF   7      // features
#define NH   128    // hidden
#define NP   96     // decoder steps
#define EROWS 8     // encoder rows/block -> 256 blocks
#define DROWS 4     // decoder rows/block -> 512 blocks (2 passes; hist LDS-resident)
#define NTHR 512
#define KE   160    // enc A/B K: [x 0..6][pad 7][h 8..135][pad 136..159]
#define KD   256    // dec A/B K: [combine 0..127][prev_h 128..255]
#define HXS  168    // h16 row stride for enc MFMA-A tile
#define CTS  264    // cath row stride in h16

typedef _Float16 h16;
typedef _Float16 h16x8 __attribute__((ext_vector_type(8)));
typedef float    f32x2 __attribute__((ext_vector_type(2)));
typedef float    f32x4 __attribute__((ext_vector_type(4)));
typedef unsigned int u32x4 __attribute__((ext_vector_type(4)));

// -------- d_ws layout (bytes). Total ~45.6 MB. --------
constexpr size_t WENC_OFF   = 0;         // h16[512][160]
constexpr size_t WDEC_OFF   = 163840;    // h16[512][256]
constexpr size_t WEFF_OFF   = 425984;    // h16[168][128]  W_att_h + W_out^T W_att_y
constexpr size_t BEFF_OFF   = 468992;    // f32[168]
constexpr size_t WCOMB_OFF  = 469760;    // f32[128]  W_out^T @ W_fin^T
constexpr size_t BCONST_OFF = 470272;    // f32[1]
constexpr size_t BENC_OFF   = 470528;    // f32[512]
constexpr size_t BDEC_OFF   = 472576;    // f32[512]
constexpr size_t ENC_OFF    = 524288;    // u32[NB][42][128]: fp8x4 (s-packed) hist, x16 scale
constexpr size_t HT_OFF     = 44564480;  // f32[NB*NH] final encoder h (1 MB)

// -------- decoder dynamic-LDS layout (bytes) --------
constexpr int HIST_OFF = 0;        // u32[4][42][128]   86016
constexpr int CATH_OFF = 86016;    // h16[2][16][CTS]   16896 -> 102912
constexpr int ATTW_OFF = 102912;   // f32[4][168]        2688 -> 105600
constexpr int WAT2_OFF = 105600;   // h16[40][128] Weff rows 128..167  10240 -> 115840
constexpr int D0_OFF   = 115840;   // f32[4][168] step-0 y-delta  2688 -> 118528
constexpr int OUTP_OFF = 118528;   // f32[8][4] out partials       128 -> 118656
constexpr int YH_OFF   = 118656;   // f32[28] yh scratch           128 -> 118784
constexpr int DSMEM    = 118784;

__device__ __forceinline__ float sigm(float x) { return 1.f / (1.f + __expf(-x)); }
__device__ __forceinline__ float tanh_(float x) {
  float e = __expf(-2.f * fabsf(x));
  return copysignf((1.f - e) / (1.f + e), x);
}

template <bool HI>
__device__ __forceinline__ unsigned int pack2_fp8(float a, float b, unsigned int old) {
#if __has_builtin(__builtin_amdgcn_cvt_pk_fp8_f32)
  return (unsigned int)__builtin_amdgcn_cvt_pk_fp8_f32(a, b, (int)old, HI);
#else
  __hip_fp8_e4m3 qa(a), qb(b);
  unsigned int pair = (unsigned int)(*(unsigned char*)&qa) |
                      ((unsigned int)(*(unsigned char*)&qb) << 8);
  return HI ? ((old & 0x0000ffffu) | (pair << 16)) : ((old & 0xffff0000u) | pair);
#endif
}
template <bool HI>
__device__ __forceinline__ f32x2 unp2(unsigned int w) {
#if __has_builtin(__builtin_amdgcn_cvt_pk_f32_fp8)
  return __builtin_amdgcn_cvt_pk_f32_fp8(w, HI);
#else
  __hip_fp8_e4m3 a, b;
  constexpr unsigned int sh = HI ? 16 : 0;
  *(unsigned char*)&a = (w >> sh) & 0xff;
  *(unsigned char*)&b = (w >> (sh + 8)) & 0xff;
  f32x2 r; r.x = (float)a; r.y = (float)b; return r;
#endif
}

// -------- setup: cast/pack weights + algebraic folds into ws --------
__global__ void setup_weights(const float* __restrict__ Wih_enc, const float* __restrict__ Whh_enc,
                              const float* __restrict__ Wih_dec, const float* __restrict__ Whh_dec,
                              const float* __restrict__ Watt, const float* __restrict__ batt,
                              const float* __restrict__ Wout, const float* __restrict__ bout,
                              const float* __restrict__ Wfin, const float* __restrict__ bfin,
                              const float* __restrict__ bihe, const float* __restrict__ bhhe,
                              const float* __restrict__ bihd, const float* __restrict__ bhhd,
                              char* __restrict__ ws) {
  int idx = blockIdx.x * blockDim.x + threadIdx.x;
  constexpr int A0 = 81920;            // enc W
  constexpr int A1 = A0 + 131072;      // dec W
  constexpr int A2 = A1 + 21504;       // Weff
  constexpr int A3 = A2 + 168;         // beff
  constexpr int A4 = A3 + 128;         // wcomb
  constexpr int A5 = A4 + 1;           // bconst
  constexpr int A6 = A5 + 512;         // biases
  if (idx < A0) {
    int n = idx / KE, k = idx % KE;
    float v = 0.f;
    if (k < NF) v = Wih_enc[n * NF + k];
    else if (k >= 8 && k < 136) v = Whh_enc[n * NH + (k - 8)];
    ((h16*)(ws + WENC_OFF))[idx] = (h16)v;
  } else if (idx < A1) {
    int i = idx - A0;
    int n = i / KD, k = i % KD;
    float v = (k < NH) ? Wih_dec[n * NH + k] : Whh_dec[n * NH + (k - NH)];
    ((h16*)(ws + WDEC_OFF))[i] = (h16)v;
  } else if (idx < A2) {
    int i = idx - A1;
    int s = i / NH, k = i % NH;
    float v = Watt[s * (NH + NF) + k];
    #pragma unroll
    for (int f = 0; f < NF; ++f)
      v += Watt[s * (NH + NF) + NH + f] * Wout[f * NH + k];
    ((h16*)(ws + WEFF_OFF))[i] = (h16)v;
  } else if (idx < A3) {
    int s = idx - A2;
    float v = batt[s];
    #pragma unroll
    for (int f = 0; f < NF; ++f)
      v += Watt[s * (NH + NF) + NH + f] * bout[f];
    ((float*)(ws + BEFF_OFF))[s] = v;
  } else if (idx < A4) {
    int k = idx - A3;
    float v = 0.f;
    #pragma unroll
    for (int f = 0; f < NF; ++f) v += Wfin[f] * Wout[f * NH + k];
    ((float*)(ws + WCOMB_OFF))[k] = v;
  } else if (idx < A5) {
    float v = bfin[0];
    #pragma unroll
    for (int f = 0; f < NF; ++f) v += bout[f] * Wfin[f];
    ((float*)(ws + BCONST_OFF))[0] = v;
  } else if (idx < A6) {
    int g = idx - A5;
    ((float*)(ws + BENC_OFF))[g] = bihe[g] + bhhe[g];
    ((float*)(ws + BDEC_OFF))[g] = bihd[g] + bhhd[g];
  }
}

// ================= encoder: 8 rows/block, 256 blocks, 1 barrier/step =================
__global__ __launch_bounds__(NTHR, 1)
void enc_kernel(const float* __restrict__ xb, const h16* __restrict__ w16enc,
                const float* __restrict__ bencp, unsigned int* __restrict__ encw,
                float* __restrict__ hT) {
  __shared__ alignas(16) h16 sh_hx[2][16][HXS];

  const int t  = threadIdx.x;
  const int r0 = blockIdx.x * EROWS;

  for (int i = t; i < 2 * 16 * HXS; i += NTHR) ((h16*)sh_hx)[i] = (h16)0.f;
  __syncthreads();
  if (t < EROWS * NF) {
    int r = t / NF, f = t - (t / NF) * NF;
    sh_hx[0][r][f] = (h16)xb[((size_t)(r0 + r) * SEQ + 0) * NF + f];
  }

  const int w  = t >> 6;
  const int l  = t & 63;
  const int lq = l >> 4;
  const int ln = l & 15;
  const int hcol = w * 16 + ln;
  const int mrow = lq * 4;
  const bool act = (lq < 2);

  const int j  = t & 3;
  const int rf = t >> 2;
  const int xr = rf / NF;
  const int xf = rf - xr * NF;

  h16x8 bfE[4][5];
  float bE[4];
  #pragma unroll
  for (int g = 0; g < 4; ++g) {
    int n = g * 128 + hcol;
    bE[g] = bencp[n];
    #pragma unroll
    for (int kt = 0; kt < 5; ++kt)
      bfE[g][kt] = *(const h16x8*)(w16enc + n * KE + kt * 32 + lq * 8);
  }

  float creg[4] = {0.f, 0.f, 0.f, 0.f};
  float hlast[4] = {0.f, 0.f, 0.f, 0.f};
  float hprev[4] = {0.f, 0.f, 0.f, 0.f};
  unsigned int hpack[4] = {0u, 0u, 0u, 0u};
  float xstash = 0.f;

  __syncthreads();

  for (int s = 0; s < SEQ; ++s) {
    const int cur = s & 1;
    if ((s & 3) == 0 && t < EROWS * NF * 4) {
      int sx = s + 1 + j;
      xstash = (sx < SEQ) ? xb[((size_t)(r0 + xr) * SEQ + sx) * NF + xf] : 0.f;
    }

    h16x8 af[5];
    #pragma unroll
    for (int kt = 0; kt < 5; ++kt)
      af[kt] = *(const h16x8*)(&sh_hx[cur][ln][kt * 32 + lq * 8]);
    f32x4 ac[4];
    #pragma unroll
    for (int g = 0; g < 4; ++g) {
      f32x4 a = {0.f, 0.f, 0.f, 0.f};
      #pragma unroll
      for (int kt = 0; kt < 5; ++kt)
        a = __builtin_amdgcn_mfma_f32_16x16x32_f16(af[kt], bfE[g][kt], a, 0, 0, 0);
      ac[g] = a;
    }

    if (act) {
      #pragma unroll
      for (int reg = 0; reg < 4; ++reg) {
        float gi = sigm(ac[0][reg] + bE[0]);
        float gf = sigm(ac[1][reg] + bE[1]);
        float gg = tanh_(ac[2][reg] + bE[2]);
        float go = sigm(ac[3][reg] + bE[3]);
        float c = gf * creg[reg] + gi * gg;
        creg[reg] = c;
        float h = go * tanh_(c);
        hlast[reg] = h;
        sh_hx[cur ^ 1][mrow + reg][8 + hcol] = (h16)h;
        float hs = h * 16.f;
        if ((s & 1) == 0) hprev[reg] = hs;
        else if ((s & 3) == 1) hpack[reg] = pack2_fp8<false>(hprev[reg], hs, hpack[reg]);
        else                   hpack[reg] = pack2_fp8<true>(hprev[reg], hs, hpack[reg]);
      }
      if ((s & 3) == 3) {
        int s4 = s >> 2;
        #pragma unroll
        for (int reg = 0; reg < 4; ++reg)
          encw[((size_t)(r0 + mrow + reg) * 42 + s4) * NH + hcol] = hpack[reg];
      }
    }
    if (t < EROWS * NF * 4 && (s & 3) == j && s + 1 < SEQ)
      sh_hx[cur ^ 1][xr][xf] = (h16)xstash;
    __syncthreads();
  }

  if (act) {
    #pragma unroll
    for (int reg = 0; reg < 4; ++reg)
      hT[(size_t)(r0 + mrow + reg) * NH + hcol] = hlast[reg];
  }
}

// ================= decoder: 4 rows/block, hist in LDS, 3 barriers/step, no loop globals ===
__global__ __launch_bounds__(NTHR, 1)
void dec_kernel(const float* __restrict__ xb, const float* __restrict__ Watt,
                const float* __restrict__ Wout, const float* __restrict__ bout,
                const h16* __restrict__ w16dec, const h16* __restrict__ weff,
                const float* __restrict__ beffp, const float* __restrict__ wcombp,
                const float* __restrict__ bconstp, const float* __restrict__ bdecp,
                const unsigned int* __restrict__ encw, const float* __restrict__ hT,
                float* __restrict__ out) {
  extern __shared__ char smem[];
  unsigned int* hist = (unsigned int*)(smem + HIST_OFF);   // [4][42][128] u32
  h16*   sh_cath  = (h16*)(smem + CATH_OFF);               // [2][16][CTS]
  float* sh_attw  = (float*)(smem + ATTW_OFF);             // [4][168] e-values
  h16*   sh_watt2 = (h16*)(smem + WAT2_OFF);               // [40][128] Weff tail
  float* sh_d0    = (float*)(smem + D0_OFF);               // [4][168] step-0 delta
  float* sh_outp  = (float*)(smem + OUTP_OFF);             // [8][4] out partials
  float* sh_yh    = (float*)(smem + YH_OFF);               // [28]

  const int t  = threadIdx.x;
  const int r0 = blockIdx.x * DROWS;

  // ---- init LDS ----
  for (int i = t; i < 2 * 16 * CTS; i += NTHR)  sh_cath[i] = (h16)0.f;
  for (int i = t; i < 40 * NH; i += NTHR)       sh_watt2[i] = weff[128 * NH + i];
  {
    const u32x4* src = (const u32x4*)(encw + (size_t)r0 * 42 * NH);
    for (int i = t; i < (DROWS * 42 * NH) / 4; i += NTHR)
      ((u32x4*)hist)[i] = src[i];
  }

  const int w  = t >> 6;
  const int l  = t & 63;
  const int lq = l >> 4;
  const int ln = l & 15;
  const int hcol = w * 16 + ln;
  const bool act = (lq == 0);   // rows 0..3 real

  // B fragments: dec gates (i,f,g) K=256; Weff tile K=128
  h16x8 bfD[3][8];
  float bD[3];
  #pragma unroll
  for (int g = 0; g < 3; ++g) {
    int n = g * 128 + hcol;
    bD[g] = bdecp[n];
    #pragma unroll
    for (int kt = 0; kt < 8; ++kt)
      bfD[g][kt] = *(const h16x8*)(w16dec + n * KD + kt * 32 + lq * 8);
  }
  h16x8 bfA[4];
  #pragma unroll
  for (int kt = 0; kt < 4; ++kt)
    bfA[kt] = *(const h16x8*)(weff + hcol * NH + kt * 32 + lq * 8);
  const float beffR = beffp[hcol];
  const int s2v = 128 + hcol;
  const float beff2 = (w < 3 && s2v < SEQ) ? beffp[s2v] : 0.f;
  const float wcombR = wcombp[hcol];
  const float bconstv = bconstp[0];

  // cell init from h_T; prev_h into cath[0]
  float creg[4] = {0.f, 0.f, 0.f, 0.f};
  if (act) {
    #pragma unroll
    for (int reg = 0; reg < 4; ++reg) {
      float hv = hT[(size_t)(r0 + reg) * NH + hcol];
      creg[reg] = hv;
      sh_cath[0 * 16 * CTS + reg * CTS + 128 + hcol] = (h16)hv;
    }
  }
  // yh[r][f] = h_T . W_out[f] + bout[f]  (one-time)
  if (t < DROWS * NF) {
    int r = t / NF, f = t - (t / NF) * NF;
    float a = bout[f];
    const float* wr = Wout + f * NH;
    const float* hp = hT + (size_t)(r0 + r) * NH;
    #pragma unroll 8
    for (int k = 0; k < NH; k += 4) {
      float4 pv = *(const float4*)(hp + k);
      float4 wv = *(const float4*)(wr + k);
      a += pv.x * wv.x + pv.y * wv.y + pv.z * wv.z + pv.w * wv.w;
    }
    sh_yh[t] = a;
  }
  __syncthreads();
  // d0[r][s] = (y0[r] - yh[r]) . W_att_y[s]  (step-0 correction)
  if (t < DROWS * SEQ) {
    int r = t / SEQ, s = t - (t / SEQ) * SEQ;
    float a = 0.f;
    #pragma unroll
    for (int f = 0; f < NF; ++f) {
      float y0f = xb[((size_t)(r0 + r) * SEQ + (SEQ - 1)) * NF + f];
      a += (y0f - sh_yh[r * NF + f]) * Watt[s * (NH + NF) + NH + f];
    }
    sh_d0[r * SEQ + s] = a;
  }
  __syncthreads();

  // D3 per-thread constants
  const int dr = t >> 7;
  const int dh = t & 127;
  const unsigned int* hrow = hist + dr * (42 * NH) + dh;
  const float* erow = sh_attw + dr * SEQ;

  for (int p = 0; p < NP; ++p) {
    const int CA = p & 1;

    // finalize previous step's output (partials written in prev D4)
    if (p > 0 && t < DROWS) {
      float a = bconstv;
      #pragma unroll
      for (int w2 = 0; w2 < 8; ++w2) a += sh_outp[w2 * 4 + t];
      out[(size_t)(r0 + t) * NP + (p - 1)] = a;
    }

    // D1: logits = prev_h @ Weff^T + beff (+d0 at p=0); e = exp(clamped)
    {
      h16x8 afA[4];
      #pragma unroll
      for (int kt = 0; kt < 4; ++kt)
        afA[kt] = *(const h16x8*)(sh_cath + CA * 16 * CTS + ln * CTS + 128 + kt * 32 + lq * 8);
      f32x4 acc = {0.f, 0.f, 0.f, 0.f};
      #pragma unroll
      for (int kt = 0; kt < 4; ++kt)
        acc = __builtin_amdgcn_mfma_f32_16x16x32_f16(afA[kt], bfA[kt], acc, 0, 0, 0);
      if (act) {
        #pragma unroll
        for (int reg = 0; reg < 4; ++reg) {
          float lg = acc[reg] + beffR;
          if (p == 0) lg += sh_d0[reg * SEQ + hcol];
          lg = fminf(fmaxf(lg, -30.f), 30.f);
          sh_attw[reg * SEQ + hcol] = __expf(lg);
        }
      }
      if (w < 3) {
        int srow = (s2v < SEQ ? s2v : SEQ - 1) - 128;
        f32x4 acc2 = {0.f, 0.f, 0.f, 0.f};
        #pragma unroll
        for (int kt = 0; kt < 4; ++kt) {
          h16x8 bf2 = *(const h16x8*)(sh_watt2 + srow * NH + kt * 32 + lq * 8);
          acc2 = __builtin_amdgcn_mfma_f32_16x16x32_f16(afA[kt], bf2, acc2, 0, 0, 0);
        }
        if (s2v < SEQ && act) {
          #pragma unroll
          for (int reg = 0; reg < 4; ++reg) {
            float lg = acc2[reg] + beff2;
            if (p == 0) lg += sh_d0[reg * SEQ + s2v];
            lg = fminf(fmaxf(lg, -30.f), 30.f);
            sh_attw[reg * SEQ + s2v] = __expf(lg);
          }
        }
      }
    }
    __syncthreads();

    // D3: combine[r][h] = (Σ_s e_s v_s)/(Σ_s e_s); thread owns (r,h)
    {
      f32x2 av = {0.f, 0.f};
      f32x2 es = {0.f, 0.f};
      #pragma unroll 6
      for (int s4 = 0; s4 < 42; ++s4) {
        unsigned int ev = hrow[s4 * NH];
        float4 e4 = *(const float4*)(erow + s4 * 4);
        f32x2 p01 = unp2<false>(ev);
        f32x2 p23 = unp2<true>(ev);
        f32x2 w01 = {e4.x, e4.y};
        f32x2 w23 = {e4.z, e4.w};
        av = w01 * p01 + av;
        av = w23 * p23 + av;
        es = es + w01;
        es = es + w23;
      }
      float inv = 0.0625f / (es.x + es.y);
      sh_cath[CA * 16 * CTS + dr * CTS + dh] = (h16)((av.x + av.y) * inv);
    }
    __syncthreads();

    // D4+D5: gates via MFMA (i,f,g); cell in-register; out-partials via wcomb
    {
      h16x8 af[8];
      #pragma unroll
      for (int kt = 0; kt < 8; ++kt)
        af[kt] = *(const h16x8*)(sh_cath + CA * 16 * CTS + ln * CTS + kt * 32 + lq * 8);
      f32x4 ag[3];
      #pragma unroll
      for (int g = 0; g < 3; ++g) {
        f32x4 a = {0.f, 0.f, 0.f, 0.f};
        #pragma unroll
        for (int kt = 0; kt < 8; ++kt)
          a = __builtin_amdgcn_mfma_f32_16x16x32_f16(af[kt], bfD[g][kt], a, 0, 0, 0);
        ag[g] = a;
      }
      if (act) {
        float contrib[4];
        #pragma unroll
        for (int reg = 0; reg < 4; ++reg) {
          float gi = sigm(ag[0][reg] + bD[0]);
          float gf = sigm(ag[1][reg] + bD[1]);
          float gg = tanh_(ag[2][reg] + bD[2]);
          float cn = gf * creg[reg] + gi * gg;
          creg[reg] = cn;
          sh_cath[(CA ^ 1) * 16 * CTS + reg * CTS + 128 + hcol] = (h16)cn;
          contrib[reg] = cn * wcombR;
        }
        #pragma unroll
        for (int reg = 0; reg < 4; ++reg) {
          float rsum = contrib[reg];
          rsum += __shfl_xor(rsum, 1);
          rsum += __shfl_xor(rsum, 2);
          rsum += __shfl_xor(rsum, 4);
          rsum += __shfl_xor(rsum, 8);
          if (l == 0) sh_outp[w * 4 + reg] = rsum;
        }
      }
    }
    __syncthreads();
  }

  // finalize last output
  if (t < DROWS) {
    float a = bconstv;
    #pragma unroll
    for (int w2 = 0; w2 < 8; ++w2) a += sh_outp[w2 * 4 + t];
    out[(size_t)(r0 + t) * NP + (NP - 1)] = a;
  }
}

extern "C" void kernel_launch(void* const* d_in, const int* in_sizes, int n_in,
                              void* d_out, int out_size, void* d_ws, size_t ws_size,
                              hipStream_t stream) {
  const float* xb      = (const float*)d_in[0];
  const float* Wih_enc = (const float*)d_in[1];
  const float* Whh_enc = (const float*)d_in[2];
  const float* bih_enc = (const float*)d_in[3];
  const float* bhh_enc = (const float*)d_in[4];
  const float* Watt    = (const float*)d_in[5];
  const float* batt    = (const float*)d_in[6];
  const float* Wih_dec = (const float*)d_in[7];
  const float* Whh_dec = (const float*)d_in[8];
  const float* bih_dec = (const float*)d_in[9];
  const float* bhh_dec = (const float*)d_in[10];
  const float* Wout    = (const float*)d_in[11];
  const float* bout    = (const float*)d_in[12];
  const float* Wfin    = (const float*)d_in[13];
  const float* bfin    = (const float*)d_in[14];
  char* ws = (char*)d_ws;  // needs ~45.6 MB

  hipFuncSetAttribute(reinterpret_cast<const void*>(dec_kernel),
                      hipFuncAttributeMaxDynamicSharedMemorySize, DSMEM);

  // 81920+131072+21504+168+128+1+512 = 235305 -> 920 blocks
  setup_weights<<<920, 256, 0, stream>>>(Wih_enc, Whh_enc, Wih_dec, Whh_dec,
                                         Watt, batt, Wout, bout, Wfin, bfin,
                                         bih_enc, bhh_enc, bih_dec, bhh_dec, ws);
  enc_kernel<<<NB / EROWS, NTHR, 0, stream>>>(
      xb, (const h16*)(ws + WENC_OFF), (const float*)(ws + BENC_OFF),
      (unsigned int*)(ws + ENC_OFF), (float*)(ws + HT_OFF));
  dec_kernel<<<NB / DROWS, NTHR, DSMEM, stream>>>(
      xb, Watt, Wout, bout,
      (const h16*)(ws + WDEC_OFF), (const h16*)(ws + WEFF_OFF),
      (const float*)(ws + BEFF_OFF), (const float*)(ws + WCOMB_OFF),
      (const float*)(ws + BCONST_OFF), (const float*)(ws + BDEC_OFF),
      (const unsigned int*)(ws + ENC_OFF), (const float*)(ws + HT_OFF),
      (float*)d_out);
}